// Round 11
// baseline (351.603 us; speedup 1.0000x reference)
//
#include <hip/hip_runtime.h>
#include <math.h>

#define NN 50000
#define NE 300000

typedef short s8v __attribute__((ext_vector_type(8)));
typedef float f4v __attribute__((ext_vector_type(4)));

__device__ inline unsigned short f2bf(float f) {
    union { float f; unsigned int u; } v; v.f = f;
    unsigned int r = v.u + 0x7FFFu + ((v.u >> 16) & 1u);
    return (unsigned short)(r >> 16);
}
__device__ inline float bf2f(unsigned short u) {
    union { unsigned int i; float f; } v; v.i = ((unsigned int)u) << 16;
    return v.f;
}

// ---------------- weight pack bodies ----------------
template<int CIN, int O>
__device__ inline void packw_feast_body(const float* __restrict__ W,
                                        unsigned short* __restrict__ wp, int t) {
    constexpr int NS = (8*CIN) / 32;
    int l = t & 63;
    int s = (t >> 6) % NS;
    int ct = t / (64 * NS);
    int c = ct*16 + (l & 15);
    int kk0 = s*32 + (l >> 4) * 8;
    union { unsigned short u[8]; s8v v; } o;
    #pragma unroll
    for (int i = 0; i < 8; ++i) {
        int kk = kk0 + i;
        int h = kk / CIN, k = kk & (CIN - 1);
        o.u[i] = f2bf(W[(size_t)k*(8*O) + h*O + c]);
    }
    *(s8v*)(wp + (size_t)t*8) = o.v;
}

__device__ inline void packw_lin_body(const float* __restrict__ W,
                                      unsigned short* __restrict__ wp, int t) {
    int l = t & 63;
    int s = (t >> 6) & 3;
    int ctg = t >> 8;
    int c = ctg*16 + (l & 15);
    int k0 = s*32 + (l >> 4) * 8;
    union { unsigned short u[8]; s8v v; } o;
    #pragma unroll
    for (int i = 0; i < 8; ++i) o.u[i] = f2bf(W[(size_t)(k0+i)*1024 + c]);
    *(s8v*)(wp + (size_t)t*8) = o.v;
}

// ---------------- mega-prep: packs + zeroing + lin1(bf16) + a1 -------------
__global__ __launch_bounds__(256) void prep_kernel(
        const float* __restrict__ l2w, unsigned short* __restrict__ w2p,
        const float* __restrict__ wf1w, unsigned short* __restrict__ wf1,
        const float* __restrict__ wf2w, unsigned short* __restrict__ wf2,
        const float* __restrict__ wf3w, unsigned short* __restrict__ wf3,
        int* __restrict__ fill, int* __restrict__ fill2,
        float* __restrict__ z, float* __restrict__ scal,
        const float* __restrict__ x, const float* __restrict__ l1w,
        const float* __restrict__ l1b, const float* __restrict__ u1,
        unsigned short* __restrict__ h1, float* __restrict__ a) {
    __shared__ float hsh[16][16];
    int b = blockIdx.x;
    int tid = threadIdx.x;
    if (b < 64)  { packw_lin_body(l2w, w2p, b*256 + tid); return; }
    b -= 64;
    if (b < 2)   { packw_feast_body<16,32>(wf1w, wf1, b*256 + tid); return; }
    b -= 2;
    if (b < 8)   { packw_feast_body<32,64>(wf2w, wf2, b*256 + tid); return; }
    b -= 8;
    if (b < 32)  { packw_feast_body<64,128>(wf3w, wf3, b*256 + tid); return; }
    b -= 32;
    if (b < 587) {
        int idx = b*256 + tid;
        if (idx < NN)            fill[idx] = 0;
        else if (idx < 2*NN)     fill2[idx - NN] = 0;
        else if (idx < 3*NN)     z[idx - 2*NN] = 0.f;
        else if (idx < 3*NN+16)  scal[idx - 3*NN] = 0.f;
        return;
    }
    b -= 587;                        // 0..3124 : lin1 + a1
    int n0 = b * 16;
    int node = n0 + (tid >> 4), col = tid & 15;
    float v = x[node*3+0]*l1w[col] + x[node*3+1]*l1w[16+col]
            + x[node*3+2]*l1w[32+col] + l1b[col];
    v = fmaxf(v, 0.f);
    h1[(size_t)node*16 + col] = f2bf(v);
    hsh[tid >> 4][col] = v;
    __syncthreads();
    if (tid < 128) {
        int t2 = tid >> 3, h = tid & 7;
        float acc = 0.f;
        #pragma unroll
        for (int k = 0; k < 16; ++k) acc += hsh[t2][k] * u1[k*8 + h];
        a[(size_t)(n0 + t2)*8 + h] = acc;
    }
}

// ---------------- CSR build ----------------
__global__ void hist_kernel(const int* __restrict__ dst, int* __restrict__ cnt) {
    int e = blockIdx.x * 256 + threadIdx.x;
    if (e < NE) atomicAdd(&cnt[dst[e]], 1);
}

__global__ void scan1_kernel(const int* __restrict__ cnt, int* __restrict__ rp,
                             int* __restrict__ bpart) {
    __shared__ int sh[256];
    int tid = threadIdx.x;
    int gid = blockIdx.x * 256 + tid;
    int v = (gid < NN) ? cnt[gid] : 0;
    sh[tid] = v;
    __syncthreads();
    for (int off = 1; off < 256; off <<= 1) {
        int t = (tid >= off) ? sh[tid - off] : 0;
        __syncthreads();
        sh[tid] += t;
        __syncthreads();
    }
    if (gid < NN) rp[gid] = sh[tid] - v;
    if (tid == 255) bpart[blockIdx.x] = sh[tid];
}

__global__ void scanfix_kernel(int* __restrict__ rp, const int* __restrict__ bpart,
                               int nblk) {
    __shared__ int sh[256];
    int tid = threadIdx.x;
    int bx = blockIdx.x;
    sh[tid] = (tid < bx && tid < nblk) ? bpart[tid] : 0;
    __syncthreads();
    for (int off = 128; off; off >>= 1) {
        if (tid < off) sh[tid] += sh[tid + off];
        __syncthreads();
    }
    int add = sh[0];
    int gid = bx * 256 + tid;
    if (gid < NN) rp[gid] += add;
    if (gid == 0) rp[NN] = NE;
}

__global__ void scatter_kernel(const int* __restrict__ src, const int* __restrict__ dst,
                               const int* __restrict__ rp, int* __restrict__ fill,
                               int* __restrict__ ssrc) {
    int e = blockIdx.x * 256 + threadIdx.x;
    if (e >= NE) return;
    int d = dst[e];
    int pos = rp[d] + atomicAdd(&fill[d], 1);
    ssrc[pos] = src[e];
}

// ---------------- fused conv: agg (q fused, LDS tile) + MFMA GEMM ----------
// 64 rows/block, 4 waves x 16 rows. Wave aggregates its 16 dsts into a
// XOR-swizzled LDS tile (af ds_read_b128 at 1KB stride would be 16-way
// conflicted otherwise), then loads its A-fragments and runs the staged GEMM.
// q-scratch reuses the bsh area (protected by the stage loop's first barrier).
template<int CIN, int O, int CH, bool AEPI>
__global__ __launch_bounds__(256) void conv_kernel(
        const unsigned short* __restrict__ hin, const float* __restrict__ a,
        const float* __restrict__ cbias,
        const int* __restrict__ rowptr, const int* __restrict__ ssrc,
        const unsigned short* __restrict__ wp, const float* __restrict__ b,
        unsigned short* __restrict__ hout,
        const float* __restrict__ unext, float* __restrict__ aout) {
    constexpr int K = 8*CIN;
    constexpr int NS = K / 32;
    constexpr int NCT = O / 16;
    constexpr int HPER = CIN / 8;
    constexpr int LG = (CIN == 16) ? 4 : (CIN == 32) ? 5 : 6;
    __shared__ unsigned short gt[64 * K];         // swizzled agg tile
    __shared__ unsigned short bsh[CH * NS * 512]; // B stage (>= 4x2KB q-scratch)
    const int l = threadIdx.x & 63;
    const int w = threadIdx.x >> 6;
    float* qsh = (float*)bsh + w*512;             // per-wave q scratch [64][8]
    const int k = l & (CIN - 1);
    const int hg = l >> LG;
    // softmax(c) per-lane constants
    float cc[8];
    #pragma unroll
    for (int h = 0; h < 8; ++h) cc[h] = cbias[h];
    float m0 = cc[0];
    #pragma unroll
    for (int h = 1; h < 8; ++h) m0 = fmaxf(m0, cc[h]);
    float ssum = 0.f;
    #pragma unroll
    for (int h = 0; h < 8; ++h) ssum += __expf(cc[h] - m0);
    float sinv = 1.f / ssum;
    float scv[HPER];
    #pragma unroll
    for (int i = 0; i < HPER; ++i) scv[i] = __expf(cc[hg*HPER + i] - m0) * sinv;

    // ---- agg phase: 16 dsts per wave ----
    for (int r16 = 0; r16 < 16; ++r16) {
        const int row = w*16 + r16;
        unsigned short* grow = gt + row * K;
        const int swz = (row & 7) << 3;
        const int d = blockIdx.x * 64 + row;
        if (d >= NN) {
            #pragma unroll
            for (int i = 0; i < HPER; ++i)
                grow[((hg*HPER + i)*CIN + k) ^ swz] = 0;
            continue;
        }
        float ad[8];
        #pragma unroll
        for (int h = 0; h < 8; ++h) ad[h] = a[(size_t)d*8 + h];
        float xd = bf2f(hin[(size_t)d*CIN + k]);
        float acc[HPER];
        #pragma unroll
        for (int i = 0; i < HPER; ++i) acc[i] = scv[i] * xd;
        const int j0 = rowptr[d], j1 = rowptr[d+1];
        for (int jb = j0; jb < j1; jb += 64) {
            int cnt = j1 - jb; if (cnt > 64) cnt = 64;
            if (l < cnt) {                          // phase 1: q per edge
                int s = ssrc[jb + l];
                const float4* as = (const float4*)(a + (size_t)s*8);
                float4 s0 = as[0], s1 = as[1];
                float lg[8] = { s0.x-ad[0]+cc[0], s0.y-ad[1]+cc[1],
                                s0.z-ad[2]+cc[2], s0.w-ad[3]+cc[3],
                                s1.x-ad[4]+cc[4], s1.y-ad[5]+cc[5],
                                s1.z-ad[6]+cc[6], s1.w-ad[7]+cc[7] };
                float m = lg[0];
                #pragma unroll
                for (int h = 1; h < 8; ++h) m = fmaxf(m, lg[h]);
                float sum = 0.f;
                #pragma unroll
                for (int h = 0; h < 8; ++h) { lg[h] = __expf(lg[h]-m); sum += lg[h]; }
                float inv = 1.f / sum;
                float4* qp = (float4*)&qsh[l*8];
                qp[0] = make_float4(lg[0]*inv, lg[1]*inv, lg[2]*inv, lg[3]*inv);
                qp[1] = make_float4(lg[4]*inv, lg[5]*inv, lg[6]*inv, lg[7]*inv);
            }
            int je = jb + cnt;                      // phase 2: gather
            int j = jb;
            for (; j + 2 <= je; j += 2) {
                int s0 = ssrc[j], s1 = ssrc[j+1];
                float xv0 = bf2f(hin[(size_t)s0*CIN + k]);
                float xv1 = bf2f(hin[(size_t)s1*CIN + k]);
                float qv0[HPER], qv1[HPER];
                if constexpr (HPER == 2) {
                    float2 t0 = *(const float2*)&qsh[(j-jb)*8 + hg*2];
                    float2 t1 = *(const float2*)&qsh[(j+1-jb)*8 + hg*2];
                    qv0[0]=t0.x; qv0[1]=t0.y; qv1[0]=t1.x; qv1[1]=t1.y;
                } else if constexpr (HPER == 4) {
                    float4 t0 = *(const float4*)&qsh[(j-jb)*8 + hg*4];
                    float4 t1 = *(const float4*)&qsh[(j+1-jb)*8 + hg*4];
                    qv0[0]=t0.x; qv0[1]=t0.y; qv0[2]=t0.z; qv0[3]=t0.w;
                    qv1[0]=t1.x; qv1[1]=t1.y; qv1[2]=t1.z; qv1[3]=t1.w;
                } else {
                    float4 t0a = *(const float4*)&qsh[(j-jb)*8];
                    float4 t0b = *(const float4*)&qsh[(j-jb)*8 + 4];
                    float4 t1a = *(const float4*)&qsh[(j+1-jb)*8];
                    float4 t1b = *(const float4*)&qsh[(j+1-jb)*8 + 4];
                    qv0[0]=t0a.x; qv0[1]=t0a.y; qv0[2]=t0a.z; qv0[3]=t0a.w;
                    qv0[4]=t0b.x; qv0[5]=t0b.y; qv0[6]=t0b.z; qv0[7]=t0b.w;
                    qv1[0]=t1a.x; qv1[1]=t1a.y; qv1[2]=t1a.z; qv1[3]=t1a.w;
                    qv1[4]=t1b.x; qv1[5]=t1b.y; qv1[6]=t1b.z; qv1[7]=t1b.w;
                }
                #pragma unroll
                for (int i = 0; i < HPER; ++i) acc[i] += qv0[i]*xv0 + qv1[i]*xv1;
            }
            if (j < je) {
                int s0 = ssrc[j];
                float xv0 = bf2f(hin[(size_t)s0*CIN + k]);
                #pragma unroll
                for (int i = 0; i < HPER; ++i)
                    acc[i] += qsh[(j-jb)*8 + hg*HPER + i] * xv0;
            }
        }
        #pragma unroll
        for (int i = 0; i < HPER; ++i)
            grow[((hg*HPER + i)*CIN + k) ^ swz] = f2bf(acc[i]);
    }

    // ---- load A fragments from own LDS strip (same wave, no barrier) ----
    const int base = blockIdx.x * 64 + w * 16;
    s8v af[NS];
    {
        const int row = w*16 + (l & 15);
        const int swz = (row & 7) << 3;
        #pragma unroll
        for (int s = 0; s < NS; ++s)
            af[s] = *(const s8v*)(gt + row*K + ((s*32 + (l >> 4)*8) ^ swz));
    }
    float invc[4];
    #pragma unroll
    for (int r = 0; r < 4; ++r) {
        int n = base + (l >> 4)*4 + r; if (n >= NN) n = NN - 1;
        invc[r] = 1.f / (float)(rowptr[n+1] - rowptr[n] + 1);
    }
    float apart[4][8];
    if constexpr (AEPI) {
        #pragma unroll
        for (int r = 0; r < 4; ++r)
            #pragma unroll
            for (int h = 0; h < 8; ++h) apart[r][h] = 0.f;
    }
    // ---- staged GEMM ----
    #pragma unroll 1
    for (int ct0 = 0; ct0 < NCT; ct0 += CH) {
        __syncthreads();                  // all waves past agg before bsh write
        const int4* sp = (const int4*)(wp + (size_t)ct0*NS*512);
        int4* dp = (int4*)bsh;
        #pragma unroll 1
        for (int i = threadIdx.x; i < CH*NS*64; i += 256) dp[i] = sp[i];
        __syncthreads();
        #pragma unroll 1
        for (int cc_ = 0; cc_ < CH; ++cc_) {
            f4v accA = {0.f,0.f,0.f,0.f}, accB = {0.f,0.f,0.f,0.f};
            #pragma unroll
            for (int s = 0; s < NS/2; ++s) {
                s8v bf = *(const s8v*)(bsh + ((size_t)(cc_*NS + s)*64 + l)*8);
                accA = __builtin_amdgcn_mfma_f32_16x16x32_bf16(af[s], bf, accA, 0, 0, 0);
            }
            #pragma unroll
            for (int s = NS/2; s < NS; ++s) {
                s8v bf = *(const s8v*)(bsh + ((size_t)(cc_*NS + s)*64 + l)*8);
                accB = __builtin_amdgcn_mfma_f32_16x16x32_bf16(af[s], bf, accB, 0, 0, 0);
            }
            int col = (ct0 + cc_)*16 + (l & 15);
            float bb = b[col];
            float uv[8];
            if constexpr (AEPI) {
                #pragma unroll
                for (int h = 0; h < 8; ++h) uv[h] = unext[col*8 + h];
            }
            #pragma unroll
            for (int r = 0; r < 4; ++r) {
                int n = base + (l >> 4)*4 + r;
                float v = fmaxf((accA[r]+accB[r])*invc[r] + bb, 0.f);
                if constexpr (AEPI) {
                    #pragma unroll
                    for (int h = 0; h < 8; ++h) apart[r][h] += v * uv[h];
                }
                if (n < NN) hout[(size_t)n*O + col] = f2bf(v);
            }
        }
    }
    if constexpr (AEPI) {
        #pragma unroll
        for (int r = 0; r < 4; ++r)
            #pragma unroll
            for (int h = 0; h < 8; ++h) {
                float v = apart[r][h];
                v += __shfl_xor(v, 1, 64);
                v += __shfl_xor(v, 2, 64);
                v += __shfl_xor(v, 4, 64);
                v += __shfl_xor(v, 8, 64);
                if ((l & 15) == 0) {
                    int n = base + (l >> 4)*4 + r;
                    if (n < NN) aout[(size_t)n*8 + h] = v;
                }
            }
    }
}

// ---------------- lin23 split-ct z reduction ----------------
__global__ __launch_bounds__(256) void lin23z_kernel(
        const unsigned short* __restrict__ h4b, const unsigned short* __restrict__ w2p,
        const float* __restrict__ b2, const float* __restrict__ w3,
        float* __restrict__ z) {
    const int l = threadIdx.x & 63;
    const int w = threadIdx.x >> 6;
    const int ctg = blockIdx.y;
    const int rowbase = blockIdx.x * 256 + w * 64;
    const int koff = (l >> 4) * 8;
    s8v bf0[4], bf1[4], bf2[4], bf3[4];
    #pragma unroll
    for (int s = 0; s < 4; ++s) {
        bf0[s] = *(const s8v*)(w2p + ((size_t)((ctg*4+0)*4 + s)*64 + l)*8);
        bf1[s] = *(const s8v*)(w2p + ((size_t)((ctg*4+1)*4 + s)*64 + l)*8);
        bf2[s] = *(const s8v*)(w2p + ((size_t)((ctg*4+2)*4 + s)*64 + l)*8);
        bf3[s] = *(const s8v*)(w2p + ((size_t)((ctg*4+3)*4 + s)*64 + l)*8);
    }
    float w3c[4], b2c[4];
    #pragma unroll
    for (int c = 0; c < 4; ++c) {
        int col = (ctg*4 + c)*16 + (l & 15);
        w3c[c] = w3[col]; b2c[c] = b2[col];
    }
    #pragma unroll 1
    for (int t = 0; t < 4; ++t) {
        int base = rowbase + t*16;
        int arow = base + (l & 15); if (arow >= NN) arow = NN - 1;
        s8v af[4];
        #pragma unroll
        for (int s = 0; s < 4; ++s)
            af[s] = *(const s8v*)(h4b + (size_t)arow*128 + s*32 + koff);
        float zp0 = 0.f, zp1 = 0.f, zp2 = 0.f, zp3 = 0.f;
        #pragma unroll
        for (int c = 0; c < 4; ++c) {
            const s8v* bf = (c == 0) ? bf0 : (c == 1) ? bf1 : (c == 2) ? bf2 : bf3;
            f4v accA = {0.f,0.f,0.f,0.f}, accB = {0.f,0.f,0.f,0.f};
            accA = __builtin_amdgcn_mfma_f32_16x16x32_bf16(af[0], bf[0], accA, 0, 0, 0);
            accA = __builtin_amdgcn_mfma_f32_16x16x32_bf16(af[1], bf[1], accA, 0, 0, 0);
            accB = __builtin_amdgcn_mfma_f32_16x16x32_bf16(af[2], bf[2], accB, 0, 0, 0);
            accB = __builtin_amdgcn_mfma_f32_16x16x32_bf16(af[3], bf[3], accB, 0, 0, 0);
            zp0 += fmaxf(accA[0]+accB[0] + b2c[c], 0.f) * w3c[c];
            zp1 += fmaxf(accA[1]+accB[1] + b2c[c], 0.f) * w3c[c];
            zp2 += fmaxf(accA[2]+accB[2] + b2c[c], 0.f) * w3c[c];
            zp3 += fmaxf(accA[3]+accB[3] + b2c[c], 0.f) * w3c[c];
        }
        #pragma unroll
        for (int m = 1; m < 16; m <<= 1) {
            zp0 += __shfl_xor(zp0, m, 64);
            zp1 += __shfl_xor(zp1, m, 64);
            zp2 += __shfl_xor(zp2, m, 64);
            zp3 += __shfl_xor(zp3, m, 64);
        }
        if ((l & 15) == 0) {
            int r0 = base + (l >> 4) * 4;
            if (r0+0 < NN) atomicAdd(&z[r0+0], zp0);
            if (r0+1 < NN) atomicAdd(&z[r0+1], zp1);
            if (r0+2 < NN) atomicAdd(&z[r0+2], zp2);
            if (r0+3 < NN) atomicAdd(&z[r0+3], zp3);
        }
    }
}

// ---------------- finish: sigmoid + balanced-BCE loss ----------------
__global__ void finish_kernel(const float* __restrict__ labels,
                              const float* __restrict__ z,
                              const float* __restrict__ b3,
                              float* __restrict__ p,
                              float* __restrict__ scal,
                              float* __restrict__ out, int nblk) {
    __shared__ float sh0[256], sh1[256], sh2[256];
    int tid = threadIdx.x;
    int n = blockIdx.x * 256 + tid;
    float pos = 0.f, sp = 0.f, sn = 0.f;
    if (n < NN) {
        float pv = 1.f / (1.f + expf(-(z[n] + b3[0])));
        p[n] = pv;
        float yv = labels[n];
        if (yv == 1.0f) { pos = 1.f; sp = -fmaxf(logf(pv), -100.f); }
        else            { sn = -fmaxf(logf(1.f - pv), -100.f); }
    }
    sh0[tid] = pos; sh1[tid] = sp; sh2[tid] = sn;
    __syncthreads();
    for (int off = 128; off; off >>= 1) {
        if (tid < off) {
            sh0[tid] += sh0[tid+off];
            sh1[tid] += sh1[tid+off];
            sh2[tid] += sh2[tid+off];
        }
        __syncthreads();
    }
    if (tid == 0) {
        atomicAdd(&scal[0], sh0[0]);
        atomicAdd(&scal[1], sh1[0]);
        atomicAdd(&scal[2], sh2[0]);
        __threadfence();
        int t = atomicAdd((int*)&scal[4], 1);
        if (t == nblk - 1) {
            float posT = atomicAdd(&scal[0], 0.f);
            float spT  = atomicAdd(&scal[1], 0.f);
            float snT  = atomicAdd(&scal[2], 0.f);
            out[0] = spT / (2.f*posT) + snT / (2.f*((float)NN - posT));
        }
    }
}

// ---------------- launch ----------------
extern "C" void kernel_launch(void* const* d_in, const int* in_sizes, int n_in,
                              void* d_out, int out_size, void* d_ws, size_t ws_size,
                              hipStream_t stream) {
    (void)in_sizes; (void)n_in; (void)out_size; (void)ws_size;
    const float* x   = (const float*)d_in[0];
    const int*   ei  = (const int*)d_in[1];
    const float* labels = (const float*)d_in[2];
    const float* l1w = (const float*)d_in[3];
    const float* l1b = (const float*)d_in[4];
    const float* cw[3] = {(const float*)d_in[5], (const float*)d_in[9],  (const float*)d_in[13]};
    const float* cu[3] = {(const float*)d_in[6], (const float*)d_in[10], (const float*)d_in[14]};
    const float* cc[3] = {(const float*)d_in[7], (const float*)d_in[11], (const float*)d_in[15]};
    const float* cb[3] = {(const float*)d_in[8], (const float*)d_in[12], (const float*)d_in[16]};
    const float* l2w = (const float*)d_in[17];
    const float* l2b = (const float*)d_in[18];
    const float* l3w = (const float*)d_in[19];
    const float* l3b = (const float*)d_in[20];
    const int* srcp = ei;
    const int* dstp = ei + NE;
    float* out = (float*)d_out;

    // ---- workspace (float units, 64B aligned) ----
    float* ws = (float*)d_ws;
    size_t off = 0;
    auto alloc = [&](size_t n) { float* p = ws + off; off += (n + 15) & ~(size_t)15; return p; };
    unsigned short* hA = (unsigned short*)alloc((size_t)NN*32);   // bf16: h1(N,16) / h3(N,64)
    unsigned short* hB = (unsigned short*)alloc((size_t)NN*64);   // bf16: h2(N,32) / h4(N,128)
    float* aA = alloc((size_t)NN*8);
    float* aB = alloc((size_t)NN*8);
    unsigned short* w2p = (unsigned short*)alloc(65536);
    unsigned short* wf1 = (unsigned short*)alloc(2048);
    unsigned short* wf2 = (unsigned short*)alloc(8192);
    unsigned short* wf3 = (unsigned short*)alloc(32768);
    float* z    = alloc(NN);
    float* scal = alloc(16);
    int* rowptr = (int*)alloc(50016);
    int* fill   = (int*)alloc(NN);
    int* fill2  = (int*)alloc(NN);
    int* ssrc   = (int*)alloc(NE);
    int* bpart  = (int*)alloc(256);

    const int SCAN_BLKS = (NN + 255) / 256;           // 196
    const int GB = (NN + 63) / 64;                    // 782
    const int PREP_BLKS = 106 + 587 + NN/16;          // 3818

    // ---- prep + CSR build ----
    prep_kernel<<<PREP_BLKS, 256, 0, stream>>>(l2w, w2p, cw[0], wf1, cw[1], wf2,
                                               cw[2], wf3, fill, fill2, z, scal,
                                               x, l1w, l1b, cu[0], hA, aA);
    hist_kernel<<<(NE+255)/256, 256, 0, stream>>>(dstp, fill);
    scan1_kernel<<<SCAN_BLKS, 256, 0, stream>>>(fill, rowptr, bpart);
    scanfix_kernel<<<SCAN_BLKS, 256, 0, stream>>>(rowptr, bpart, SCAN_BLKS);
    scatter_kernel<<<(NE+255)/256, 256, 0, stream>>>(srcp, dstp, rowptr, fill2, ssrc);

    // ---- fused convs (agg+GEMM); a ping-pongs to avoid read/write race ----
    conv_kernel<16,32,2,true ><<<GB, 256, 0, stream>>>(hA, aA, cc[0], rowptr, ssrc,
                                                       wf1, cb[0], hB, cu[1], aB);
    conv_kernel<32,64,1,true ><<<GB, 256, 0, stream>>>(hB, aB, cc[1], rowptr, ssrc,
                                                       wf2, cb[1], hA, cu[2], aA);
    conv_kernel<64,128,1,false><<<GB, 256, 0, stream>>>(hA, aA, cc[2], rowptr, ssrc,
                                                        wf3, cb[2], hB, nullptr, nullptr);

    // ---- lin2+lin3 z reduction, then sigmoid+loss ----
    lin23z_kernel<<<dim3((NN+255)/256, 16), 256, 0, stream>>>(hB, w2p, l2b, l3w, z);
    finish_kernel<<<SCAN_BLKS, 256, 0, stream>>>(labels, z, l3b, out + 1, scal, out, SCAN_BLKS);
}

// Round 12
// 242.902 us; speedup vs baseline: 1.4475x; 1.4475x over previous
//
#include <hip/hip_runtime.h>
#include <math.h>

#define NN 50000
#define NE 300000

typedef short s8v __attribute__((ext_vector_type(8)));
typedef float f4v __attribute__((ext_vector_type(4)));

__device__ inline unsigned short f2bf(float f) {
    union { float f; unsigned int u; } v; v.f = f;
    unsigned int r = v.u + 0x7FFFu + ((v.u >> 16) & 1u);
    return (unsigned short)(r >> 16);
}
__device__ inline float bf2f(unsigned short u) {
    union { unsigned int i; float f; } v; v.i = ((unsigned int)u) << 16;
    return v.f;
}

// ---------------- weight pack bodies ----------------
template<int CIN, int O>
__device__ inline void packw_feast_body(const float* __restrict__ W,
                                        unsigned short* __restrict__ wp, int t) {
    constexpr int NS = (8*CIN) / 32;
    int l = t & 63;
    int s = (t >> 6) % NS;
    int ct = t / (64 * NS);
    int c = ct*16 + (l & 15);
    int kk0 = s*32 + (l >> 4) * 8;
    union { unsigned short u[8]; s8v v; } o;
    #pragma unroll
    for (int i = 0; i < 8; ++i) {
        int kk = kk0 + i;
        int h = kk / CIN, k = kk & (CIN - 1);
        o.u[i] = f2bf(W[(size_t)k*(8*O) + h*O + c]);
    }
    *(s8v*)(wp + (size_t)t*8) = o.v;
}

__device__ inline void packw_lin_body(const float* __restrict__ W,
                                      unsigned short* __restrict__ wp, int t) {
    int l = t & 63;
    int s = (t >> 6) & 3;
    int ctg = t >> 8;
    int c = ctg*16 + (l & 15);
    int k0 = s*32 + (l >> 4) * 8;
    union { unsigned short u[8]; s8v v; } o;
    #pragma unroll
    for (int i = 0; i < 8; ++i) o.u[i] = f2bf(W[(size_t)(k0+i)*1024 + c]);
    *(s8v*)(wp + (size_t)t*8) = o.v;
}

// ---------------- mega-prep: packs + zeroing + lin1(bf16) + a1 -------------
__global__ __launch_bounds__(256) void prep_kernel(
        const float* __restrict__ l2w, unsigned short* __restrict__ w2p,
        const float* __restrict__ wf1w, unsigned short* __restrict__ wf1,
        const float* __restrict__ wf2w, unsigned short* __restrict__ wf2,
        const float* __restrict__ wf3w, unsigned short* __restrict__ wf3,
        int* __restrict__ fill, int* __restrict__ fill2,
        float* __restrict__ z, float* __restrict__ scal,
        const float* __restrict__ x, const float* __restrict__ l1w,
        const float* __restrict__ l1b, const float* __restrict__ u1,
        unsigned short* __restrict__ h1, float* __restrict__ a) {
    __shared__ float hsh[16][16];
    int b = blockIdx.x;
    int tid = threadIdx.x;
    if (b < 64)  { packw_lin_body(l2w, w2p, b*256 + tid); return; }
    b -= 64;
    if (b < 2)   { packw_feast_body<16,32>(wf1w, wf1, b*256 + tid); return; }
    b -= 2;
    if (b < 8)   { packw_feast_body<32,64>(wf2w, wf2, b*256 + tid); return; }
    b -= 8;
    if (b < 32)  { packw_feast_body<64,128>(wf3w, wf3, b*256 + tid); return; }
    b -= 32;
    if (b < 587) {
        int idx = b*256 + tid;
        if (idx < NN)            fill[idx] = 0;
        else if (idx < 2*NN)     fill2[idx - NN] = 0;
        else if (idx < 3*NN)     z[idx - 2*NN] = 0.f;
        else if (idx < 3*NN+16)  scal[idx - 3*NN] = 0.f;
        return;
    }
    b -= 587;                        // 0..3124 : lin1 + a1
    int n0 = b * 16;
    int node = n0 + (tid >> 4), col = tid & 15;
    float v = x[node*3+0]*l1w[col] + x[node*3+1]*l1w[16+col]
            + x[node*3+2]*l1w[32+col] + l1b[col];
    v = fmaxf(v, 0.f);
    h1[(size_t)node*16 + col] = f2bf(v);
    hsh[tid >> 4][col] = v;
    __syncthreads();
    if (tid < 128) {
        int t2 = tid >> 3, h = tid & 7;
        float acc = 0.f;
        #pragma unroll
        for (int k = 0; k < 16; ++k) acc += hsh[t2][k] * u1[k*8 + h];
        a[(size_t)(n0 + t2)*8 + h] = acc;
    }
}

// ---------------- CSR build ----------------
__global__ void hist_kernel(const int* __restrict__ dst, int* __restrict__ cnt) {
    int e = blockIdx.x * 256 + threadIdx.x;
    if (e < NE) atomicAdd(&cnt[dst[e]], 1);
}

__global__ void scan1_kernel(const int* __restrict__ cnt, int* __restrict__ rp,
                             int* __restrict__ bpart) {
    __shared__ int sh[256];
    int tid = threadIdx.x;
    int gid = blockIdx.x * 256 + tid;
    int v = (gid < NN) ? cnt[gid] : 0;
    sh[tid] = v;
    __syncthreads();
    for (int off = 1; off < 256; off <<= 1) {
        int t = (tid >= off) ? sh[tid - off] : 0;
        __syncthreads();
        sh[tid] += t;
        __syncthreads();
    }
    if (gid < NN) rp[gid] = sh[tid] - v;
    if (tid == 255) bpart[blockIdx.x] = sh[tid];
}

__global__ void scanfix_kernel(int* __restrict__ rp, const int* __restrict__ bpart,
                               int nblk) {
    __shared__ int sh[256];
    int tid = threadIdx.x;
    int bx = blockIdx.x;
    sh[tid] = (tid < bx && tid < nblk) ? bpart[tid] : 0;
    __syncthreads();
    for (int off = 128; off; off >>= 1) {
        if (tid < off) sh[tid] += sh[tid + off];
        __syncthreads();
    }
    int add = sh[0];
    int gid = bx * 256 + tid;
    if (gid < NN) rp[gid] += add;
    if (gid == 0) rp[NN] = NE;
}

__global__ void scatter_kernel(const int* __restrict__ src, const int* __restrict__ dst,
                               const int* __restrict__ rp, int* __restrict__ fill,
                               int* __restrict__ ssrc) {
    int e = blockIdx.x * 256 + threadIdx.x;
    if (e >= NE) return;
    int d = dst[e];
    int pos = rp[d] + atomicAdd(&fill[d], 1);
    ssrc[pos] = src[e];
}

// ---------------- fused q + agg (round-10 structure, 4-wide gather) --------
template<int CIN>
__global__ __launch_bounds__(256) void agg_kernel(
        const unsigned short* __restrict__ hin, const float* __restrict__ a,
        const float* __restrict__ cbias,
        const int* __restrict__ rowptr, const int* __restrict__ ssrc,
        unsigned short* __restrict__ g) {
    constexpr int HPER = CIN / 8;
    constexpr int LG = (CIN == 16) ? 4 : (CIN == 32) ? 5 : 6;
    __shared__ float qsh[4][64][8];
    const int lane = threadIdx.x & 63;
    const int w = threadIdx.x >> 6;
    const int d = blockIdx.x * 4 + w;
    const int k = lane & (CIN - 1);
    const int hg = lane >> LG;
    float cc[8], ad[8];
    #pragma unroll
    for (int h = 0; h < 8; ++h) { cc[h] = cbias[h]; ad[h] = a[(size_t)d*8 + h]; }
    float m0 = cc[0];
    #pragma unroll
    for (int h = 1; h < 8; ++h) m0 = fmaxf(m0, cc[h]);
    float ssum = 0.f;
    #pragma unroll
    for (int h = 0; h < 8; ++h) ssum += __expf(cc[h] - m0);
    float sinv = 1.f / ssum;
    float xd = bf2f(hin[(size_t)d*CIN + k]);
    float acc[HPER];
    #pragma unroll
    for (int i = 0; i < HPER; ++i)
        acc[i] = __expf(cc[hg*HPER + i] - m0) * sinv * xd;
    const int j0 = rowptr[d], j1 = rowptr[d+1];
    for (int jb = j0; jb < j1; jb += 64) {
        int cnt = j1 - jb; if (cnt > 64) cnt = 64;
        if (lane < cnt) {                          // phase 1: q per edge
            int s = ssrc[jb + lane];
            const float4* as = (const float4*)(a + (size_t)s*8);
            float4 s0 = as[0], s1 = as[1];
            float lg[8] = { s0.x-ad[0]+cc[0], s0.y-ad[1]+cc[1],
                            s0.z-ad[2]+cc[2], s0.w-ad[3]+cc[3],
                            s1.x-ad[4]+cc[4], s1.y-ad[5]+cc[5],
                            s1.z-ad[6]+cc[6], s1.w-ad[7]+cc[7] };
            float m = lg[0];
            #pragma unroll
            for (int h = 1; h < 8; ++h) m = fmaxf(m, lg[h]);
            float sum = 0.f;
            #pragma unroll
            for (int h = 0; h < 8; ++h) { lg[h] = __expf(lg[h]-m); sum += lg[h]; }
            float inv = 1.f / sum;
            float4* qp = (float4*)&qsh[w][lane][0];
            qp[0] = make_float4(lg[0]*inv, lg[1]*inv, lg[2]*inv, lg[3]*inv);
            qp[1] = make_float4(lg[4]*inv, lg[5]*inv, lg[6]*inv, lg[7]*inv);
        }
        int je = jb + cnt;                          // phase 2: gather, 4-wide
        int j = jb;
        for (; j + 4 <= je; j += 4) {
            int s0 = ssrc[j],   s1 = ssrc[j+1];
            int s2 = ssrc[j+2], s3 = ssrc[j+3];
            float xv0 = bf2f(hin[(size_t)s0*CIN + k]);
            float xv1 = bf2f(hin[(size_t)s1*CIN + k]);
            float xv2 = bf2f(hin[(size_t)s2*CIN + k]);
            float xv3 = bf2f(hin[(size_t)s3*CIN + k]);
            #pragma unroll
            for (int i = 0; i < HPER; ++i) {
                acc[i] += qsh[w][j-jb][hg*HPER + i]   * xv0
                        + qsh[w][j+1-jb][hg*HPER + i] * xv1
                        + qsh[w][j+2-jb][hg*HPER + i] * xv2
                        + qsh[w][j+3-jb][hg*HPER + i] * xv3;
            }
        }
        for (; j < je; ++j) {
            int s0 = ssrc[j];
            float xv0 = bf2f(hin[(size_t)s0*CIN + k]);
            #pragma unroll
            for (int i = 0; i < HPER; ++i)
                acc[i] += qsh[w][j-jb][hg*HPER + i] * xv0;
        }
    }
    #pragma unroll
    for (int i = 0; i < HPER; ++i)
        g[(size_t)d*(8*CIN) + (hg*HPER + i)*CIN + k] = f2bf(acc[i]);
}

// ---------------- feast GEMM (bf16 out, optional a-epilogue) ---------------
template<int K, int O, int CH, bool AEPI>
__global__ __launch_bounds__(256) void gemm_feast(
        const unsigned short* __restrict__ g, const unsigned short* __restrict__ wp,
        const int* __restrict__ rowptr, const float* __restrict__ b,
        unsigned short* __restrict__ hout,
        const float* __restrict__ unext, float* __restrict__ aout) {
    constexpr int NS = K / 32;
    constexpr int NCT = O / 16;
    __shared__ unsigned short bsh[CH*NS*64*8];
    const int l = threadIdx.x & 63;
    const int w = threadIdx.x >> 6;
    const int base = blockIdx.x * 64 + w * 16;
    int arow = base + (l & 15); if (arow >= NN) arow = NN - 1;
    const int koff = (l >> 4) * 8;
    s8v af[NS];
    #pragma unroll
    for (int s = 0; s < NS; ++s)
        af[s] = *(const s8v*)(g + (size_t)arow*K + s*32 + koff);
    float invc[4];
    #pragma unroll
    for (int r = 0; r < 4; ++r) {
        int n = base + (l >> 4)*4 + r; if (n >= NN) n = NN - 1;
        invc[r] = 1.f / (float)(rowptr[n+1] - rowptr[n] + 1);
    }
    float apart[4][8];
    if constexpr (AEPI) {
        #pragma unroll
        for (int r = 0; r < 4; ++r)
            #pragma unroll
            for (int h = 0; h < 8; ++h) apart[r][h] = 0.f;
    }
    #pragma unroll 1
    for (int ct0 = 0; ct0 < NCT; ct0 += CH) {
        __syncthreads();
        const int4* sp = (const int4*)(wp + (size_t)ct0*NS*512);
        int4* dp = (int4*)bsh;
        #pragma unroll 1
        for (int i = threadIdx.x; i < CH*NS*64; i += 256) dp[i] = sp[i];
        __syncthreads();
        #pragma unroll 1
        for (int cc = 0; cc < CH; ++cc) {
            f4v accA = {0.f,0.f,0.f,0.f}, accB = {0.f,0.f,0.f,0.f};
            #pragma unroll
            for (int s = 0; s < NS/2; ++s) {
                s8v bf = *(const s8v*)(bsh + ((size_t)(cc*NS + s)*64 + l)*8);
                accA = __builtin_amdgcn_mfma_f32_16x16x32_bf16(af[s], bf, accA, 0, 0, 0);
            }
            #pragma unroll
            for (int s = NS/2; s < NS; ++s) {
                s8v bf = *(const s8v*)(bsh + ((size_t)(cc*NS + s)*64 + l)*8);
                accB = __builtin_amdgcn_mfma_f32_16x16x32_bf16(af[s], bf, accB, 0, 0, 0);
            }
            int col = (ct0 + cc)*16 + (l & 15);
            float bb = b[col];
            float uv[8];
            if constexpr (AEPI) {
                #pragma unroll
                for (int h = 0; h < 8; ++h) uv[h] = unext[col*8 + h];
            }
            #pragma unroll
            for (int r = 0; r < 4; ++r) {
                int n = base + (l >> 4)*4 + r;
                float v = fmaxf((accA[r]+accB[r])*invc[r] + bb, 0.f);
                if constexpr (AEPI) {
                    #pragma unroll
                    for (int h = 0; h < 8; ++h) apart[r][h] += v * uv[h];
                }
                if (n < NN) hout[(size_t)n*O + col] = f2bf(v);
            }
        }
    }
    if constexpr (AEPI) {
        #pragma unroll
        for (int r = 0; r < 4; ++r)
            #pragma unroll
            for (int h = 0; h < 8; ++h) {
                float v = apart[r][h];
                v += __shfl_xor(v, 1, 64);
                v += __shfl_xor(v, 2, 64);
                v += __shfl_xor(v, 4, 64);
                v += __shfl_xor(v, 8, 64);
                if ((l & 15) == 0) {
                    int n = base + (l >> 4)*4 + r;
                    if (n < NN) aout[(size_t)n*8 + h] = v;
                }
            }
    }
}

// ---------------- lin23 split-ct z reduction ----------------
__global__ __launch_bounds__(256) void lin23z_kernel(
        const unsigned short* __restrict__ h4b, const unsigned short* __restrict__ w2p,
        const float* __restrict__ b2, const float* __restrict__ w3,
        float* __restrict__ z) {
    const int l = threadIdx.x & 63;
    const int w = threadIdx.x >> 6;
    const int ctg = blockIdx.y;
    const int rowbase = blockIdx.x * 256 + w * 64;
    const int koff = (l >> 4) * 8;
    s8v bf0[4], bf1[4], bf2[4], bf3[4];
    #pragma unroll
    for (int s = 0; s < 4; ++s) {
        bf0[s] = *(const s8v*)(w2p + ((size_t)((ctg*4+0)*4 + s)*64 + l)*8);
        bf1[s] = *(const s8v*)(w2p + ((size_t)((ctg*4+1)*4 + s)*64 + l)*8);
        bf2[s] = *(const s8v*)(w2p + ((size_t)((ctg*4+2)*4 + s)*64 + l)*8);
        bf3[s] = *(const s8v*)(w2p + ((size_t)((ctg*4+3)*4 + s)*64 + l)*8);
    }
    float w3c[4], b2c[4];
    #pragma unroll
    for (int c = 0; c < 4; ++c) {
        int col = (ctg*4 + c)*16 + (l & 15);
        w3c[c] = w3[col]; b2c[c] = b2[col];
    }
    #pragma unroll 1
    for (int t = 0; t < 4; ++t) {
        int base = rowbase + t*16;
        int arow = base + (l & 15); if (arow >= NN) arow = NN - 1;
        s8v af[4];
        #pragma unroll
        for (int s = 0; s < 4; ++s)
            af[s] = *(const s8v*)(h4b + (size_t)arow*128 + s*32 + koff);
        float zp0 = 0.f, zp1 = 0.f, zp2 = 0.f, zp3 = 0.f;
        #pragma unroll
        for (int c = 0; c < 4; ++c) {
            const s8v* bf = (c == 0) ? bf0 : (c == 1) ? bf1 : (c == 2) ? bf2 : bf3;
            f4v accA = {0.f,0.f,0.f,0.f}, accB = {0.f,0.f,0.f,0.f};
            accA = __builtin_amdgcn_mfma_f32_16x16x32_bf16(af[0], bf[0], accA, 0, 0, 0);
            accA = __builtin_amdgcn_mfma_f32_16x16x32_bf16(af[1], bf[1], accA, 0, 0, 0);
            accB = __builtin_amdgcn_mfma_f32_16x16x32_bf16(af[2], bf[2], accB, 0, 0, 0);
            accB = __builtin_amdgcn_mfma_f32_16x16x32_bf16(af[3], bf[3], accB, 0, 0, 0);
            zp0 += fmaxf(accA[0]+accB[0] + b2c[c], 0.f) * w3c[c];
            zp1 += fmaxf(accA[1]+accB[1] + b2c[c], 0.f) * w3c[c];
            zp2 += fmaxf(accA[2]+accB[2] + b2c[c], 0.f) * w3c[c];
            zp3 += fmaxf(accA[3]+accB[3] + b2c[c], 0.f) * w3c[c];
        }
        #pragma unroll
        for (int m = 1; m < 16; m <<= 1) {
            zp0 += __shfl_xor(zp0, m, 64);
            zp1 += __shfl_xor(zp1, m, 64);
            zp2 += __shfl_xor(zp2, m, 64);
            zp3 += __shfl_xor(zp3, m, 64);
        }
        if ((l & 15) == 0) {
            int r0 = base + (l >> 4) * 4;
            if (r0+0 < NN) atomicAdd(&z[r0+0], zp0);
            if (r0+1 < NN) atomicAdd(&z[r0+1], zp1);
            if (r0+2 < NN) atomicAdd(&z[r0+2], zp2);
            if (r0+3 < NN) atomicAdd(&z[r0+3], zp3);
        }
    }
}

// ---------------- finish: sigmoid + balanced-BCE loss ----------------
__global__ void finish_kernel(const float* __restrict__ labels,
                              const float* __restrict__ z,
                              const float* __restrict__ b3,
                              float* __restrict__ p,
                              float* __restrict__ scal,
                              float* __restrict__ out, int nblk) {
    __shared__ float sh0[256], sh1[256], sh2[256];
    int tid = threadIdx.x;
    int n = blockIdx.x * 256 + tid;
    float pos = 0.f, sp = 0.f, sn = 0.f;
    if (n < NN) {
        float pv = 1.f / (1.f + expf(-(z[n] + b3[0])));
        p[n] = pv;
        float yv = labels[n];
        if (yv == 1.0f) { pos = 1.f; sp = -fmaxf(logf(pv), -100.f); }
        else            { sn = -fmaxf(logf(1.f - pv), -100.f); }
    }
    sh0[tid] = pos; sh1[tid] = sp; sh2[tid] = sn;
    __syncthreads();
    for (int off = 128; off; off >>= 1) {
        if (tid < off) {
            sh0[tid] += sh0[tid+off];
            sh1[tid] += sh1[tid+off];
            sh2[tid] += sh2[tid+off];
        }
        __syncthreads();
    }
    if (tid == 0) {
        atomicAdd(&scal[0], sh0[0]);
        atomicAdd(&scal[1], sh1[0]);
        atomicAdd(&scal[2], sh2[0]);
        __threadfence();
        int t = atomicAdd((int*)&scal[4], 1);
        if (t == nblk - 1) {
            float posT = atomicAdd(&scal[0], 0.f);
            float spT  = atomicAdd(&scal[1], 0.f);
            float snT  = atomicAdd(&scal[2], 0.f);
            out[0] = spT / (2.f*posT) + snT / (2.f*((float)NN - posT));
        }
    }
}

// ---------------- launch ----------------
extern "C" void kernel_launch(void* const* d_in, const int* in_sizes, int n_in,
                              void* d_out, int out_size, void* d_ws, size_t ws_size,
                              hipStream_t stream) {
    (void)in_sizes; (void)n_in; (void)out_size; (void)ws_size;
    const float* x   = (const float*)d_in[0];
    const int*   ei  = (const int*)d_in[1];
    const float* labels = (const float*)d_in[2];
    const float* l1w = (const float*)d_in[3];
    const float* l1b = (const float*)d_in[4];
    const float* cw[3] = {(const float*)d_in[5], (const float*)d_in[9],  (const float*)d_in[13]};
    const float* cu[3] = {(const float*)d_in[6], (const float*)d_in[10], (const float*)d_in[14]};
    const float* cc[3] = {(const float*)d_in[7], (const float*)d_in[11], (const float*)d_in[15]};
    const float* cb[3] = {(const float*)d_in[8], (const float*)d_in[12], (const float*)d_in[16]};
    const float* l2w = (const float*)d_in[17];
    const float* l2b = (const float*)d_in[18];
    const float* l3w = (const float*)d_in[19];
    const float* l3b = (const float*)d_in[20];
    const int* srcp = ei;
    const int* dstp = ei + NE;
    float* out = (float*)d_out;

    // ---- workspace (float units, 64B aligned) ----
    float* ws = (float*)d_ws;
    size_t off = 0;
    auto alloc = [&](size_t n) { float* p = ws + off; off += (n + 15) & ~(size_t)15; return p; };
    unsigned short* hA = (unsigned short*)alloc((size_t)NN*32);   // bf16: h1(N,16) / h3(N,64)
    unsigned short* hB = (unsigned short*)alloc((size_t)NN*64);   // bf16: h2(N,32) / h4(N,128)
    float* a  = alloc((size_t)NN*8);
    unsigned short* g   = (unsigned short*)alloc((size_t)NN*256);
    unsigned short* w2p = (unsigned short*)alloc(65536);
    unsigned short* wf1 = (unsigned short*)alloc(2048);
    unsigned short* wf2 = (unsigned short*)alloc(8192);
    unsigned short* wf3 = (unsigned short*)alloc(32768);
    float* z    = alloc(NN);
    float* scal = alloc(16);
    int* rowptr = (int*)alloc(50016);
    int* fill   = (int*)alloc(NN);
    int* fill2  = (int*)alloc(NN);
    int* ssrc   = (int*)alloc(NE);
    int* bpart  = (int*)alloc(256);

    const int SCAN_BLKS = (NN + 255) / 256;           // 196
    const int GB = (NN + 63) / 64;                    // 782
    const int PREP_BLKS = 106 + 587 + NN/16;          // 3818

    // ---- prep + CSR build ----
    prep_kernel<<<PREP_BLKS, 256, 0, stream>>>(l2w, w2p, cw[0], wf1, cw[1], wf2,
                                               cw[2], wf3, fill, fill2, z, scal,
                                               x, l1w, l1b, cu[0], hA, a);
    hist_kernel<<<(NE+255)/256, 256, 0, stream>>>(dstp, fill);
    scan1_kernel<<<SCAN_BLKS, 256, 0, stream>>>(fill, rowptr, bpart);
    scanfix_kernel<<<SCAN_BLKS, 256, 0, stream>>>(rowptr, bpart, SCAN_BLKS);
    scatter_kernel<<<(NE+255)/256, 256, 0, stream>>>(srcp, dstp, rowptr, fill2, ssrc);

    // ---- conv1: cin=16 -> O=32 (hA -> hB); epilogue a2 ----
    agg_kernel<16><<<NN/4, 256, 0, stream>>>(hA, a, cc[0], rowptr, ssrc, g);
    gemm_feast<128,32,2,true><<<GB, 256, 0, stream>>>(g, wf1, rowptr, cb[0], hB, cu[1], a);

    // ---- conv2: cin=32 -> O=64 (hB -> hA); epilogue a3 ----
    agg_kernel<32><<<NN/4, 256, 0, stream>>>(hB, a, cc[1], rowptr, ssrc, g);
    gemm_feast<256,64,4,true><<<GB, 256, 0, stream>>>(g, wf2, rowptr, cb[1], hA, cu[2], a);

    // ---- conv3: cin=64 -> O=128 (hA -> hB) ----
    agg_kernel<64><<<NN/4, 256, 0, stream>>>(hA, a, cc[2], rowptr, ssrc, g);
    gemm_feast<512,128,2,false><<<GB, 256, 0, stream>>>(g, wf3, rowptr, cb[2], hB, nullptr, nullptr);

    // ---- lin2+lin3 z reduction, then sigmoid+loss ----
    lin23z_kernel<<<dim3((NN+255)/256, 16), 256, 0, stream>>>(hB, w2p, l2b, l3w, z);
    finish_kernel<<<SCAN_BLKS, 256, 0, stream>>>(labels, z, l3b, out + 1, scal, out, SCAN_BLKS);
}

// Round 13
// 228.590 us; speedup vs baseline: 1.5381x; 1.0626x over previous
//
#include <hip/hip_runtime.h>
#include <math.h>

#define NN 50000
#define NE 300000

typedef short s8v __attribute__((ext_vector_type(8)));
typedef float f4v __attribute__((ext_vector_type(4)));

__device__ inline unsigned short f2bf(float f) {
    union { float f; unsigned int u; } v; v.f = f;
    unsigned int r = v.u + 0x7FFFu + ((v.u >> 16) & 1u);
    return (unsigned short)(r >> 16);
}
__device__ inline float bf2f(unsigned short u) {
    union { unsigned int i; float f; } v; v.i = ((unsigned int)u) << 16;
    return v.f;
}

// ---------------- weight pack bodies ----------------
template<int CIN, int O>
__device__ inline void packw_feast_body(const float* __restrict__ W,
                                        unsigned short* __restrict__ wp, int t) {
    constexpr int NS = (8*CIN) / 32;
    int l = t & 63;
    int s = (t >> 6) % NS;
    int ct = t / (64 * NS);
    int c = ct*16 + (l & 15);
    int kk0 = s*32 + (l >> 4) * 8;
    union { unsigned short u[8]; s8v v; } o;
    #pragma unroll
    for (int i = 0; i < 8; ++i) {
        int kk = kk0 + i;
        int h = kk / CIN, k = kk & (CIN - 1);
        o.u[i] = f2bf(W[(size_t)k*(8*O) + h*O + c]);
    }
    *(s8v*)(wp + (size_t)t*8) = o.v;
}

__device__ inline void packw_lin_body(const float* __restrict__ W,
                                      unsigned short* __restrict__ wp, int t) {
    int l = t & 63;
    int s = (t >> 6) & 3;
    int ctg = t >> 8;
    int c = ctg*16 + (l & 15);
    int k0 = s*32 + (l >> 4) * 8;
    union { unsigned short u[8]; s8v v; } o;
    #pragma unroll
    for (int i = 0; i < 8; ++i) o.u[i] = f2bf(W[(size_t)(k0+i)*1024 + c]);
    *(s8v*)(wp + (size_t)t*8) = o.v;
}

// ---------------- mega-prep: packs + zeroing + lin1(bf16) + a1 -------------
__global__ __launch_bounds__(256) void prep_kernel(
        const float* __restrict__ l2w, unsigned short* __restrict__ w2p,
        const float* __restrict__ wf1w, unsigned short* __restrict__ wf1,
        const float* __restrict__ wf2w, unsigned short* __restrict__ wf2,
        const float* __restrict__ wf3w, unsigned short* __restrict__ wf3,
        int* __restrict__ fill, int* __restrict__ fill2,
        float* __restrict__ z, float* __restrict__ scal,
        const float* __restrict__ x, const float* __restrict__ l1w,
        const float* __restrict__ l1b, const float* __restrict__ u1,
        unsigned short* __restrict__ h1, float* __restrict__ a) {
    __shared__ float hsh[16][16];
    int b = blockIdx.x;
    int tid = threadIdx.x;
    if (b < 64)  { packw_lin_body(l2w, w2p, b*256 + tid); return; }
    b -= 64;
    if (b < 2)   { packw_feast_body<16,32>(wf1w, wf1, b*256 + tid); return; }
    b -= 2;
    if (b < 8)   { packw_feast_body<32,64>(wf2w, wf2, b*256 + tid); return; }
    b -= 8;
    if (b < 32)  { packw_feast_body<64,128>(wf3w, wf3, b*256 + tid); return; }
    b -= 32;
    if (b < 587) {
        int idx = b*256 + tid;
        if (idx < NN)            fill[idx] = 0;
        else if (idx < 2*NN)     fill2[idx - NN] = 0;
        else if (idx < 3*NN)     z[idx - 2*NN] = 0.f;
        else if (idx < 3*NN+16)  scal[idx - 3*NN] = 0.f;
        return;
    }
    b -= 587;                        // 0..3124 : lin1 + a1
    int n0 = b * 16;
    int node = n0 + (tid >> 4), col = tid & 15;
    float v = x[node*3+0]*l1w[col] + x[node*3+1]*l1w[16+col]
            + x[node*3+2]*l1w[32+col] + l1b[col];
    v = fmaxf(v, 0.f);
    h1[(size_t)node*16 + col] = f2bf(v);
    hsh[tid >> 4][col] = v;
    __syncthreads();
    if (tid < 128) {
        int t2 = tid >> 3, h = tid & 7;
        float acc = 0.f;
        #pragma unroll
        for (int k = 0; k < 16; ++k) acc += hsh[t2][k] * u1[k*8 + h];
        a[(size_t)(n0 + t2)*8 + h] = acc;
    }
}

// ---------------- CSR build ----------------
__global__ void hist_kernel(const int* __restrict__ dst, int* __restrict__ cnt) {
    int e = blockIdx.x * 256 + threadIdx.x;
    if (e < NE) atomicAdd(&cnt[dst[e]], 1);
}

__global__ void scan1_kernel(const int* __restrict__ cnt, int* __restrict__ rp,
                             int* __restrict__ bpart) {
    __shared__ int sh[256];
    int tid = threadIdx.x;
    int gid = blockIdx.x * 256 + tid;
    int v = (gid < NN) ? cnt[gid] : 0;
    sh[tid] = v;
    __syncthreads();
    for (int off = 1; off < 256; off <<= 1) {
        int t = (tid >= off) ? sh[tid - off] : 0;
        __syncthreads();
        sh[tid] += t;
        __syncthreads();
    }
    if (gid < NN) rp[gid] = sh[tid] - v;
    if (tid == 255) bpart[blockIdx.x] = sh[tid];
}

__global__ void scanfix_kernel(int* __restrict__ rp, const int* __restrict__ bpart,
                               int nblk) {
    __shared__ int sh[256];
    int tid = threadIdx.x;
    int bx = blockIdx.x;
    sh[tid] = (tid < bx && tid < nblk) ? bpart[tid] : 0;
    __syncthreads();
    for (int off = 128; off; off >>= 1) {
        if (tid < off) sh[tid] += sh[tid + off];
        __syncthreads();
    }
    int add = sh[0];
    int gid = bx * 256 + tid;
    if (gid < NN) rp[gid] += add;
    if (gid == 0) rp[NN] = NE;
}

__global__ void scatter_kernel(const int* __restrict__ src, const int* __restrict__ dst,
                               const int* __restrict__ rp, int* __restrict__ fill,
                               int* __restrict__ ssrc) {
    int e = blockIdx.x * 256 + threadIdx.x;
    if (e >= NE) return;
    int d = dst[e];
    int pos = rp[d] + atomicAdd(&fill[d], 1);
    ssrc[pos] = src[e];
}

// ---------------- fused q + agg (src + q stashed in LDS, vector q reads) ---
template<int CIN>
__global__ __launch_bounds__(256) void agg_kernel(
        const unsigned short* __restrict__ hin, const float* __restrict__ a,
        const float* __restrict__ cbias,
        const int* __restrict__ rowptr, const int* __restrict__ ssrc,
        unsigned short* __restrict__ g) {
    constexpr int HPER = CIN / 8;
    constexpr int LG = (CIN == 16) ? 4 : (CIN == 32) ? 5 : 6;
    __shared__ float qsh[4][64][8];
    __shared__ int   ssh[4][64];
    const int lane = threadIdx.x & 63;
    const int w = threadIdx.x >> 6;
    const int d = blockIdx.x * 4 + w;
    const int k = lane & (CIN - 1);
    const int hg = lane >> LG;
    float cc[8], ad[8];
    #pragma unroll
    for (int h = 0; h < 8; ++h) { cc[h] = cbias[h]; ad[h] = a[(size_t)d*8 + h]; }
    float m0 = cc[0];
    #pragma unroll
    for (int h = 1; h < 8; ++h) m0 = fmaxf(m0, cc[h]);
    float ssum = 0.f;
    #pragma unroll
    for (int h = 0; h < 8; ++h) ssum += __expf(cc[h] - m0);
    float sinv = 1.f / ssum;
    const unsigned short* hk = hin + k;
    float xd = bf2f(hk[(size_t)d*CIN]);
    float acc[HPER];
    #pragma unroll
    for (int i = 0; i < HPER; ++i)
        acc[i] = __expf(cc[hg*HPER + i] - m0) * sinv * xd;
    const int j0 = rowptr[d], j1 = rowptr[d+1];
    for (int jb = j0; jb < j1; jb += 64) {
        int cnt = j1 - jb; if (cnt > 64) cnt = 64;
        if (lane < cnt) {                          // phase 1: q + src per edge
            int s = ssrc[jb + lane];
            ssh[w][lane] = s;
            const float4* as = (const float4*)(a + (size_t)s*8);
            float4 s0 = as[0], s1 = as[1];
            float lg[8] = { s0.x-ad[0]+cc[0], s0.y-ad[1]+cc[1],
                            s0.z-ad[2]+cc[2], s0.w-ad[3]+cc[3],
                            s1.x-ad[4]+cc[4], s1.y-ad[5]+cc[5],
                            s1.z-ad[6]+cc[6], s1.w-ad[7]+cc[7] };
            float m = lg[0];
            #pragma unroll
            for (int h = 1; h < 8; ++h) m = fmaxf(m, lg[h]);
            float sum = 0.f;
            #pragma unroll
            for (int h = 0; h < 8; ++h) { lg[h] = __expf(lg[h]-m); sum += lg[h]; }
            float inv = 1.f / sum;
            float4* qp = (float4*)&qsh[w][lane][0];
            qp[0] = make_float4(lg[0]*inv, lg[1]*inv, lg[2]*inv, lg[3]*inv);
            qp[1] = make_float4(lg[4]*inv, lg[5]*inv, lg[6]*inv, lg[7]*inv);
        }
        int je = jb + cnt;                          // phase 2: gather, 4-wide
        int j = jb;
        for (; j + 4 <= je; j += 4) {
            int o0 = j - jb;
            int s0 = ssh[w][o0],   s1 = ssh[w][o0+1];
            int s2 = ssh[w][o0+2], s3 = ssh[w][o0+3];
            float xv0 = bf2f(hk[(size_t)s0*CIN]);
            float xv1 = bf2f(hk[(size_t)s1*CIN]);
            float xv2 = bf2f(hk[(size_t)s2*CIN]);
            float xv3 = bf2f(hk[(size_t)s3*CIN]);
            if constexpr (HPER == 2) {
                float2 q0 = *(const float2*)&qsh[w][o0][hg*2];
                float2 q1 = *(const float2*)&qsh[w][o0+1][hg*2];
                float2 q2 = *(const float2*)&qsh[w][o0+2][hg*2];
                float2 q3 = *(const float2*)&qsh[w][o0+3][hg*2];
                acc[0] += q0.x*xv0 + q1.x*xv1 + q2.x*xv2 + q3.x*xv3;
                acc[1] += q0.y*xv0 + q1.y*xv1 + q2.y*xv2 + q3.y*xv3;
            } else if constexpr (HPER == 4) {
                float4 q0 = *(const float4*)&qsh[w][o0][hg*4];
                float4 q1 = *(const float4*)&qsh[w][o0+1][hg*4];
                float4 q2 = *(const float4*)&qsh[w][o0+2][hg*4];
                float4 q3 = *(const float4*)&qsh[w][o0+3][hg*4];
                acc[0] += q0.x*xv0 + q1.x*xv1 + q2.x*xv2 + q3.x*xv3;
                acc[1] += q0.y*xv0 + q1.y*xv1 + q2.y*xv2 + q3.y*xv3;
                acc[2] += q0.z*xv0 + q1.z*xv1 + q2.z*xv2 + q3.z*xv3;
                acc[3] += q0.w*xv0 + q1.w*xv1 + q2.w*xv2 + q3.w*xv3;
            } else {
                float4 q0a = *(const float4*)&qsh[w][o0][0];
                float4 q0b = *(const float4*)&qsh[w][o0][4];
                float4 q1a = *(const float4*)&qsh[w][o0+1][0];
                float4 q1b = *(const float4*)&qsh[w][o0+1][4];
                float4 q2a = *(const float4*)&qsh[w][o0+2][0];
                float4 q2b = *(const float4*)&qsh[w][o0+2][4];
                float4 q3a = *(const float4*)&qsh[w][o0+3][0];
                float4 q3b = *(const float4*)&qsh[w][o0+3][4];
                acc[0] += q0a.x*xv0 + q1a.x*xv1 + q2a.x*xv2 + q3a.x*xv3;
                acc[1] += q0a.y*xv0 + q1a.y*xv1 + q2a.y*xv2 + q3a.y*xv3;
                acc[2] += q0a.z*xv0 + q1a.z*xv1 + q2a.z*xv2 + q3a.z*xv3;
                acc[3] += q0a.w*xv0 + q1a.w*xv1 + q2a.w*xv2 + q3a.w*xv3;
                acc[4] += q0b.x*xv0 + q1b.x*xv1 + q2b.x*xv2 + q3b.x*xv3;
                acc[5] += q0b.y*xv0 + q1b.y*xv1 + q2b.y*xv2 + q3b.y*xv3;
                acc[6] += q0b.z*xv0 + q1b.z*xv1 + q2b.z*xv2 + q3b.z*xv3;
                acc[7] += q0b.w*xv0 + q1b.w*xv1 + q2b.w*xv2 + q3b.w*xv3;
            }
        }
        for (; j < je; ++j) {
            int o0 = j - jb;
            int s0 = ssh[w][o0];
            float xv0 = bf2f(hk[(size_t)s0*CIN]);
            #pragma unroll
            for (int i = 0; i < HPER; ++i)
                acc[i] += qsh[w][o0][hg*HPER + i] * xv0;
        }
    }
    #pragma unroll
    for (int i = 0; i < HPER; ++i)
        g[(size_t)d*(8*CIN) + (hg*HPER + i)*CIN + k] = f2bf(acc[i]);
}

// ---------------- feast GEMM (bf16 out, optional a-epilogue) ---------------
template<int K, int O, int CH, bool AEPI>
__global__ __launch_bounds__(256) void gemm_feast(
        const unsigned short* __restrict__ g, const unsigned short* __restrict__ wp,
        const int* __restrict__ rowptr, const float* __restrict__ b,
        unsigned short* __restrict__ hout,
        const float* __restrict__ unext, float* __restrict__ aout) {
    constexpr int NS = K / 32;
    constexpr int NCT = O / 16;
    __shared__ unsigned short bsh[CH*NS*64*8];
    const int l = threadIdx.x & 63;
    const int w = threadIdx.x >> 6;
    const int base = blockIdx.x * 64 + w * 16;
    int arow = base + (l & 15); if (arow >= NN) arow = NN - 1;
    const int koff = (l >> 4) * 8;
    s8v af[NS];
    #pragma unroll
    for (int s = 0; s < NS; ++s)
        af[s] = *(const s8v*)(g + (size_t)arow*K + s*32 + koff);
    float invc[4];
    #pragma unroll
    for (int r = 0; r < 4; ++r) {
        int n = base + (l >> 4)*4 + r; if (n >= NN) n = NN - 1;
        invc[r] = 1.f / (float)(rowptr[n+1] - rowptr[n] + 1);
    }
    float apart[4][8];
    if constexpr (AEPI) {
        #pragma unroll
        for (int r = 0; r < 4; ++r)
            #pragma unroll
            for (int h = 0; h < 8; ++h) apart[r][h] = 0.f;
    }
    #pragma unroll 1
    for (int ct0 = 0; ct0 < NCT; ct0 += CH) {
        __syncthreads();
        const int4* sp = (const int4*)(wp + (size_t)ct0*NS*512);
        int4* dp = (int4*)bsh;
        #pragma unroll 1
        for (int i = threadIdx.x; i < CH*NS*64; i += 256) dp[i] = sp[i];
        __syncthreads();
        #pragma unroll 1
        for (int cc = 0; cc < CH; ++cc) {
            f4v accA = {0.f,0.f,0.f,0.f}, accB = {0.f,0.f,0.f,0.f};
            #pragma unroll
            for (int s = 0; s < NS/2; ++s) {
                s8v bf = *(const s8v*)(bsh + ((size_t)(cc*NS + s)*64 + l)*8);
                accA = __builtin_amdgcn_mfma_f32_16x16x32_bf16(af[s], bf, accA, 0, 0, 0);
            }
            #pragma unroll
            for (int s = NS/2; s < NS; ++s) {
                s8v bf = *(const s8v*)(bsh + ((size_t)(cc*NS + s)*64 + l)*8);
                accB = __builtin_amdgcn_mfma_f32_16x16x32_bf16(af[s], bf, accB, 0, 0, 0);
            }
            int col = (ct0 + cc)*16 + (l & 15);
            float bb = b[col];
            float uv[8];
            if constexpr (AEPI) {
                #pragma unroll
                for (int h = 0; h < 8; ++h) uv[h] = unext[col*8 + h];
            }
            #pragma unroll
            for (int r = 0; r < 4; ++r) {
                int n = base + (l >> 4)*4 + r;
                float v = fmaxf((accA[r]+accB[r])*invc[r] + bb, 0.f);
                if constexpr (AEPI) {
                    #pragma unroll
                    for (int h = 0; h < 8; ++h) apart[r][h] += v * uv[h];
                }
                if (n < NN) hout[(size_t)n*O + col] = f2bf(v);
            }
        }
    }
    if constexpr (AEPI) {
        #pragma unroll
        for (int r = 0; r < 4; ++r)
            #pragma unroll
            for (int h = 0; h < 8; ++h) {
                float v = apart[r][h];
                v += __shfl_xor(v, 1, 64);
                v += __shfl_xor(v, 2, 64);
                v += __shfl_xor(v, 4, 64);
                v += __shfl_xor(v, 8, 64);
                if ((l & 15) == 0) {
                    int n = base + (l >> 4)*4 + r;
                    if (n < NN) aout[(size_t)n*8 + h] = v;
                }
            }
    }
}

// ---------------- lin23 split-ct z reduction (512 rows/block) --------------
__global__ __launch_bounds__(256) void lin23z_kernel(
        const unsigned short* __restrict__ h4b, const unsigned short* __restrict__ w2p,
        const float* __restrict__ b2, const float* __restrict__ w3,
        float* __restrict__ z) {
    const int l = threadIdx.x & 63;
    const int w = threadIdx.x >> 6;
    const int ctg = blockIdx.y;
    const int rowbase = blockIdx.x * 512 + w * 128;
    const int koff = (l >> 4) * 8;
    s8v bf0[4], bf1[4], bf2[4], bf3[4];
    #pragma unroll
    for (int s = 0; s < 4; ++s) {
        bf0[s] = *(const s8v*)(w2p + ((size_t)((ctg*4+0)*4 + s)*64 + l)*8);
        bf1[s] = *(const s8v*)(w2p + ((size_t)((ctg*4+1)*4 + s)*64 + l)*8);
        bf2[s] = *(const s8v*)(w2p + ((size_t)((ctg*4+2)*4 + s)*64 + l)*8);
        bf3[s] = *(const s8v*)(w2p + ((size_t)((ctg*4+3)*4 + s)*64 + l)*8);
    }
    float w3c[4], b2c[4];
    #pragma unroll
    for (int c = 0; c < 4; ++c) {
        int col = (ctg*4 + c)*16 + (l & 15);
        w3c[c] = w3[col]; b2c[c] = b2[col];
    }
    #pragma unroll 1
    for (int t = 0; t < 8; ++t) {
        int base = rowbase + t*16;
        if (base >= NN) break;
        int arow = base + (l & 15); if (arow >= NN) arow = NN - 1;
        s8v af[4];
        #pragma unroll
        for (int s = 0; s < 4; ++s)
            af[s] = *(const s8v*)(h4b + (size_t)arow*128 + s*32 + koff);
        float zp0 = 0.f, zp1 = 0.f, zp2 = 0.f, zp3 = 0.f;
        #pragma unroll
        for (int c = 0; c < 4; ++c) {
            const s8v* bf = (c == 0) ? bf0 : (c == 1) ? bf1 : (c == 2) ? bf2 : bf3;
            f4v accA = {0.f,0.f,0.f,0.f}, accB = {0.f,0.f,0.f,0.f};
            accA = __builtin_amdgcn_mfma_f32_16x16x32_bf16(af[0], bf[0], accA, 0, 0, 0);
            accA = __builtin_amdgcn_mfma_f32_16x16x32_bf16(af[1], bf[1], accA, 0, 0, 0);
            accB = __builtin_amdgcn_mfma_f32_16x16x32_bf16(af[2], bf[2], accB, 0, 0, 0);
            accB = __builtin_amdgcn_mfma_f32_16x16x32_bf16(af[3], bf[3], accB, 0, 0, 0);
            zp0 += fmaxf(accA[0]+accB[0] + b2c[c], 0.f) * w3c[c];
            zp1 += fmaxf(accA[1]+accB[1] + b2c[c], 0.f) * w3c[c];
            zp2 += fmaxf(accA[2]+accB[2] + b2c[c], 0.f) * w3c[c];
            zp3 += fmaxf(accA[3]+accB[3] + b2c[c], 0.f) * w3c[c];
        }
        #pragma unroll
        for (int m = 1; m < 16; m <<= 1) {
            zp0 += __shfl_xor(zp0, m, 64);
            zp1 += __shfl_xor(zp1, m, 64);
            zp2 += __shfl_xor(zp2, m, 64);
            zp3 += __shfl_xor(zp3, m, 64);
        }
        if ((l & 15) == 0) {
            int r0 = base + (l >> 4) * 4;
            if (r0+0 < NN) atomicAdd(&z[r0+0], zp0);
            if (r0+1 < NN) atomicAdd(&z[r0+1], zp1);
            if (r0+2 < NN) atomicAdd(&z[r0+2], zp2);
            if (r0+3 < NN) atomicAdd(&z[r0+3], zp3);
        }
    }
}

// ---------------- finish: sigmoid + balanced-BCE loss ----------------
__global__ void finish_kernel(const float* __restrict__ labels,
                              const float* __restrict__ z,
                              const float* __restrict__ b3,
                              float* __restrict__ p,
                              float* __restrict__ scal,
                              float* __restrict__ out, int nblk) {
    __shared__ float sh0[256], sh1[256], sh2[256];
    int tid = threadIdx.x;
    int n = blockIdx.x * 256 + tid;
    float pos = 0.f, sp = 0.f, sn = 0.f;
    if (n < NN) {
        float pv = 1.f / (1.f + expf(-(z[n] + b3[0])));
        p[n] = pv;
        float yv = labels[n];
        if (yv == 1.0f) { pos = 1.f; sp = -fmaxf(logf(pv), -100.f); }
        else            { sn = -fmaxf(logf(1.f - pv), -100.f); }
    }
    sh0[tid] = pos; sh1[tid] = sp; sh2[tid] = sn;
    __syncthreads();
    for (int off = 128; off; off >>= 1) {
        if (tid < off) {
            sh0[tid] += sh0[tid+off];
            sh1[tid] += sh1[tid+off];
            sh2[tid] += sh2[tid+off];
        }
        __syncthreads();
    }
    if (tid == 0) {
        atomicAdd(&scal[0], sh0[0]);
        atomicAdd(&scal[1], sh1[0]);
        atomicAdd(&scal[2], sh2[0]);
        __threadfence();
        int t = atomicAdd((int*)&scal[4], 1);
        if (t == nblk - 1) {
            float posT = atomicAdd(&scal[0], 0.f);
            float spT  = atomicAdd(&scal[1], 0.f);
            float snT  = atomicAdd(&scal[2], 0.f);
            out[0] = spT / (2.f*posT) + snT / (2.f*((float)NN - posT));
        }
    }
}

// ---------------- launch ----------------
extern "C" void kernel_launch(void* const* d_in, const int* in_sizes, int n_in,
                              void* d_out, int out_size, void* d_ws, size_t ws_size,
                              hipStream_t stream) {
    (void)in_sizes; (void)n_in; (void)out_size; (void)ws_size;
    const float* x   = (const float*)d_in[0];
    const int*   ei  = (const int*)d_in[1];
    const float* labels = (const float*)d_in[2];
    const float* l1w = (const float*)d_in[3];
    const float* l1b = (const float*)d_in[4];
    const float* cw[3] = {(const float*)d_in[5], (const float*)d_in[9],  (const float*)d_in[13]};
    const float* cu[3] = {(const float*)d_in[6], (const float*)d_in[10], (const float*)d_in[14]};
    const float* cc[3] = {(const float*)d_in[7], (const float*)d_in[11], (const float*)d_in[15]};
    const float* cb[3] = {(const float*)d_in[8], (const float*)d_in[12], (const float*)d_in[16]};
    const float* l2w = (const float*)d_in[17];
    const float* l2b = (const float*)d_in[18];
    const float* l3w = (const float*)d_in[19];
    const float* l3b = (const float*)d_in[20];
    const int* srcp = ei;
    const int* dstp = ei + NE;
    float* out = (float*)d_out;

    // ---- workspace (float units, 64B aligned) ----
    float* ws = (float*)d_ws;
    size_t off = 0;
    auto alloc = [&](size_t n) { float* p = ws + off; off += (n + 15) & ~(size_t)15; return p; };
    unsigned short* hA = (unsigned short*)alloc((size_t)NN*32);   // bf16: h1(N,16) / h3(N,64)
    unsigned short* hB = (unsigned short*)alloc((size_t)NN*64);   // bf16: h2(N,32) / h4(N,128)
    float* a  = alloc((size_t)NN*8);
    unsigned short* g   = (unsigned short*)alloc((size_t)NN*256);
    unsigned short* w2p = (unsigned short*)alloc(65536);
    unsigned short* wf1 = (unsigned short*)alloc(2048);
    unsigned short* wf2 = (unsigned short*)alloc(8192);
    unsigned short* wf3 = (unsigned short*)alloc(32768);
    float* z    = alloc(NN);
    float* scal = alloc(16);
    int* rowptr = (int*)alloc(50016);
    int* fill   = (int*)alloc(NN);
    int* fill2  = (int*)alloc(NN);
    int* ssrc   = (int*)alloc(NE);
    int* bpart  = (int*)alloc(256);

    const int SCAN_BLKS = (NN + 255) / 256;           // 196
    const int GB = (NN + 63) / 64;                    // 782
    const int PREP_BLKS = 106 + 587 + NN/16;          // 3818

    // ---- prep + CSR build ----
    prep_kernel<<<PREP_BLKS, 256, 0, stream>>>(l2w, w2p, cw[0], wf1, cw[1], wf2,
                                               cw[2], wf3, fill, fill2, z, scal,
                                               x, l1w, l1b, cu[0], hA, a);
    hist_kernel<<<(NE+255)/256, 256, 0, stream>>>(dstp, fill);
    scan1_kernel<<<SCAN_BLKS, 256, 0, stream>>>(fill, rowptr, bpart);
    scanfix_kernel<<<SCAN_BLKS, 256, 0, stream>>>(rowptr, bpart, SCAN_BLKS);
    scatter_kernel<<<(NE+255)/256, 256, 0, stream>>>(srcp, dstp, rowptr, fill2, ssrc);

    // ---- conv1: cin=16 -> O=32 (hA -> hB); epilogue a2 ----
    agg_kernel<16><<<NN/4, 256, 0, stream>>>(hA, a, cc[0], rowptr, ssrc, g);
    gemm_feast<128,32,2,true><<<GB, 256, 0, stream>>>(g, wf1, rowptr, cb[0], hB, cu[1], a);

    // ---- conv2: cin=32 -> O=64 (hB -> hA); epilogue a3 ----
    agg_kernel<32><<<NN/4, 256, 0, stream>>>(hB, a, cc[1], rowptr, ssrc, g);
    gemm_feast<256,64,4,true><<<GB, 256, 0, stream>>>(g, wf2, rowptr, cb[1], hA, cu[2], a);

    // ---- conv3: cin=64 -> O=128 (hA -> hB) ----
    agg_kernel<64><<<NN/4, 256, 0, stream>>>(hA, a, cc[2], rowptr, ssrc, g);
    gemm_feast<512,128,2,false><<<GB, 256, 0, stream>>>(g, wf3, rowptr, cb[2], hB, nullptr, nullptr);

    // ---- lin2+lin3 z reduction, then sigmoid+loss ----
    lin23z_kernel<<<dim3((NN+511)/512, 16), 256, 0, stream>>>(hB, w2p, l2b, l3w, z);
    finish_kernel<<<SCAN_BLKS, 256, 0, stream>>>(labels, z, l3b, out + 1, scal, out, SCAN_BLKS);
}

// Round 14
// 227.408 us; speedup vs baseline: 1.5461x; 1.0052x over previous
//
#include <hip/hip_runtime.h>
#include <math.h>

#define NN 50000
#define NE 300000

typedef short s8v __attribute__((ext_vector_type(8)));
typedef float f4v __attribute__((ext_vector_type(4)));

__device__ inline unsigned short f2bf(float f) {
    union { float f; unsigned int u; } v; v.f = f;
    unsigned int r = v.u + 0x7FFFu + ((v.u >> 16) & 1u);
    return (unsigned short)(r >> 16);
}
__device__ inline float bf2f(unsigned short u) {
    union { unsigned int i; float f; } v; v.i = ((unsigned int)u) << 16;
    return v.f;
}

// ---------------- weight pack bodies ----------------
template<int CIN, int O>
__device__ inline void packw_feast_body(const float* __restrict__ W,
                                        unsigned short* __restrict__ wp, int t) {
    constexpr int NS = (8*CIN) / 32;
    int l = t & 63;
    int s = (t >> 6) % NS;
    int ct = t / (64 * NS);
    int c = ct*16 + (l & 15);
    int kk0 = s*32 + (l >> 4) * 8;
    union { unsigned short u[8]; s8v v; } o;
    #pragma unroll
    for (int i = 0; i < 8; ++i) {
        int kk = kk0 + i;
        int h = kk / CIN, k = kk & (CIN - 1);
        o.u[i] = f2bf(W[(size_t)k*(8*O) + h*O + c]);
    }
    *(s8v*)(wp + (size_t)t*8) = o.v;
}

__device__ inline void packw_lin_body(const float* __restrict__ W,
                                      unsigned short* __restrict__ wp, int t) {
    int l = t & 63;
    int s = (t >> 6) & 3;
    int ctg = t >> 8;
    int c = ctg*16 + (l & 15);
    int k0 = s*32 + (l >> 4) * 8;
    union { unsigned short u[8]; s8v v; } o;
    #pragma unroll
    for (int i = 0; i < 8; ++i) o.u[i] = f2bf(W[(size_t)(k0+i)*1024 + c]);
    *(s8v*)(wp + (size_t)t*8) = o.v;
}

// ---------------- mega-prep: packs + zeroing + lin1(bf16, 64/blk) + a1 -----
__global__ __launch_bounds__(256) void prep_kernel(
        const float* __restrict__ l2w, unsigned short* __restrict__ w2p,
        const float* __restrict__ wf1w, unsigned short* __restrict__ wf1,
        const float* __restrict__ wf2w, unsigned short* __restrict__ wf2,
        const float* __restrict__ wf3w, unsigned short* __restrict__ wf3,
        int* __restrict__ fill, int* __restrict__ fill2,
        float* __restrict__ z, float* __restrict__ scal,
        const float* __restrict__ x, const float* __restrict__ l1w,
        const float* __restrict__ l1b, const float* __restrict__ u1,
        unsigned short* __restrict__ h1, float* __restrict__ a) {
    __shared__ float hsh[64][16];
    int b = blockIdx.x;
    int tid = threadIdx.x;
    if (b < 64)  { packw_lin_body(l2w, w2p, b*256 + tid); return; }
    b -= 64;
    if (b < 2)   { packw_feast_body<16,32>(wf1w, wf1, b*256 + tid); return; }
    b -= 2;
    if (b < 8)   { packw_feast_body<32,64>(wf2w, wf2, b*256 + tid); return; }
    b -= 8;
    if (b < 32)  { packw_feast_body<64,128>(wf3w, wf3, b*256 + tid); return; }
    b -= 32;
    if (b < 587) {
        int idx = b*256 + tid;
        if (idx < NN)            fill[idx] = 0;
        else if (idx < 2*NN)     fill2[idx - NN] = 0;
        else if (idx < 3*NN)     z[idx - 2*NN] = 0.f;
        else if (idx < 3*NN+16)  scal[idx - 3*NN] = 0.f;
        return;
    }
    b -= 587;                        // 0..781 : lin1 + a1 (64 nodes/block)
    int n0 = b * 64;
    #pragma unroll
    for (int it = 0; it < 4; ++it) {
        int i = it*256 + tid;
        int node = n0 + (i >> 4), col = i & 15;
        if (node < NN) {
            float v = x[node*3+0]*l1w[col] + x[node*3+1]*l1w[16+col]
                    + x[node*3+2]*l1w[32+col] + l1b[col];
            v = fmaxf(v, 0.f);
            h1[(size_t)node*16 + col] = f2bf(v);
            hsh[i >> 4][col] = v;
        }
    }
    __syncthreads();
    #pragma unroll
    for (int it = 0; it < 2; ++it) {
        int i = it*256 + tid;
        int t2 = i >> 3, h = i & 7;
        int node = n0 + t2;
        if (node < NN) {
            float acc = 0.f;
            #pragma unroll
            for (int k = 0; k < 16; ++k) acc += hsh[t2][k] * u1[k*8 + h];
            a[(size_t)node*8 + h] = acc;
        }
    }
}

// ---------------- CSR build ----------------
__global__ void hist_kernel(const int* __restrict__ dst, int* __restrict__ cnt) {
    int e = blockIdx.x * 256 + threadIdx.x;
    if (e < NE) atomicAdd(&cnt[dst[e]], 1);
}

__global__ void scan1_kernel(const int* __restrict__ cnt, int* __restrict__ rp,
                             int* __restrict__ bpart) {
    __shared__ int sh[256];
    int tid = threadIdx.x;
    int gid = blockIdx.x * 256 + tid;
    int v = (gid < NN) ? cnt[gid] : 0;
    sh[tid] = v;
    __syncthreads();
    for (int off = 1; off < 256; off <<= 1) {
        int t = (tid >= off) ? sh[tid - off] : 0;
        __syncthreads();
        sh[tid] += t;
        __syncthreads();
    }
    if (gid < NN) rp[gid] = sh[tid] - v;
    if (tid == 255) bpart[blockIdx.x] = sh[tid];
}

__global__ void scanfix_kernel(int* __restrict__ rp, const int* __restrict__ bpart,
                               int nblk) {
    __shared__ int sh[256];
    int tid = threadIdx.x;
    int bx = blockIdx.x;
    sh[tid] = (tid < bx && tid < nblk) ? bpart[tid] : 0;
    __syncthreads();
    for (int off = 128; off; off >>= 1) {
        if (tid < off) sh[tid] += sh[tid + off];
        __syncthreads();
    }
    int add = sh[0];
    int gid = bx * 256 + tid;
    if (gid < NN) rp[gid] += add;
    if (gid == 0) rp[NN] = NE;
}

__global__ void scatter_kernel(const int* __restrict__ src, const int* __restrict__ dst,
                               const int* __restrict__ rp, int* __restrict__ fill,
                               int* __restrict__ ssrc) {
    int e = blockIdx.x * 256 + threadIdx.x;
    if (e >= NE) return;
    int d = dst[e];
    int pos = rp[d] + atomicAdd(&fill[d], 1);
    ssrc[pos] = src[e];
}

// ---------------- fused q + agg (src + q stashed in LDS, vector q reads) ---
template<int CIN>
__global__ __launch_bounds__(256) void agg_kernel(
        const unsigned short* __restrict__ hin, const float* __restrict__ a,
        const float* __restrict__ cbias,
        const int* __restrict__ rowptr, const int* __restrict__ ssrc,
        unsigned short* __restrict__ g) {
    constexpr int HPER = CIN / 8;
    constexpr int LG = (CIN == 16) ? 4 : (CIN == 32) ? 5 : 6;
    __shared__ float qsh[4][64][8];
    __shared__ int   ssh[4][64];
    const int lane = threadIdx.x & 63;
    const int w = threadIdx.x >> 6;
    const int d = blockIdx.x * 4 + w;
    const int k = lane & (CIN - 1);
    const int hg = lane >> LG;
    float cc[8], ad[8];
    #pragma unroll
    for (int h = 0; h < 8; ++h) { cc[h] = cbias[h]; ad[h] = a[(size_t)d*8 + h]; }
    float m0 = cc[0];
    #pragma unroll
    for (int h = 1; h < 8; ++h) m0 = fmaxf(m0, cc[h]);
    float ssum = 0.f;
    #pragma unroll
    for (int h = 0; h < 8; ++h) ssum += __expf(cc[h] - m0);
    float sinv = 1.f / ssum;
    const unsigned short* hk = hin + k;
    float xd = bf2f(hk[(size_t)d*CIN]);
    float acc[HPER];
    #pragma unroll
    for (int i = 0; i < HPER; ++i)
        acc[i] = __expf(cc[hg*HPER + i] - m0) * sinv * xd;
    const int j0 = rowptr[d], j1 = rowptr[d+1];
    for (int jb = j0; jb < j1; jb += 64) {
        int cnt = j1 - jb; if (cnt > 64) cnt = 64;
        if (lane < cnt) {                          // phase 1: q + src per edge
            int s = ssrc[jb + lane];
            ssh[w][lane] = s;
            const float4* as = (const float4*)(a + (size_t)s*8);
            float4 s0 = as[0], s1 = as[1];
            float lg[8] = { s0.x-ad[0]+cc[0], s0.y-ad[1]+cc[1],
                            s0.z-ad[2]+cc[2], s0.w-ad[3]+cc[3],
                            s1.x-ad[4]+cc[4], s1.y-ad[5]+cc[5],
                            s1.z-ad[6]+cc[6], s1.w-ad[7]+cc[7] };
            float m = lg[0];
            #pragma unroll
            for (int h = 1; h < 8; ++h) m = fmaxf(m, lg[h]);
            float sum = 0.f;
            #pragma unroll
            for (int h = 0; h < 8; ++h) { lg[h] = __expf(lg[h]-m); sum += lg[h]; }
            float inv = 1.f / sum;
            float4* qp = (float4*)&qsh[w][lane][0];
            qp[0] = make_float4(lg[0]*inv, lg[1]*inv, lg[2]*inv, lg[3]*inv);
            qp[1] = make_float4(lg[4]*inv, lg[5]*inv, lg[6]*inv, lg[7]*inv);
        }
        int je = jb + cnt;                          // phase 2: gather 4/2/1-wide
        int j = jb;
        for (; j + 4 <= je; j += 4) {
            int o0 = j - jb;
            int s0 = ssh[w][o0],   s1 = ssh[w][o0+1];
            int s2 = ssh[w][o0+2], s3 = ssh[w][o0+3];
            float xv0 = bf2f(hk[(size_t)s0*CIN]);
            float xv1 = bf2f(hk[(size_t)s1*CIN]);
            float xv2 = bf2f(hk[(size_t)s2*CIN]);
            float xv3 = bf2f(hk[(size_t)s3*CIN]);
            if constexpr (HPER == 2) {
                float2 q0 = *(const float2*)&qsh[w][o0][hg*2];
                float2 q1 = *(const float2*)&qsh[w][o0+1][hg*2];
                float2 q2 = *(const float2*)&qsh[w][o0+2][hg*2];
                float2 q3 = *(const float2*)&qsh[w][o0+3][hg*2];
                acc[0] += q0.x*xv0 + q1.x*xv1 + q2.x*xv2 + q3.x*xv3;
                acc[1] += q0.y*xv0 + q1.y*xv1 + q2.y*xv2 + q3.y*xv3;
            } else if constexpr (HPER == 4) {
                float4 q0 = *(const float4*)&qsh[w][o0][hg*4];
                float4 q1 = *(const float4*)&qsh[w][o0+1][hg*4];
                float4 q2 = *(const float4*)&qsh[w][o0+2][hg*4];
                float4 q3 = *(const float4*)&qsh[w][o0+3][hg*4];
                acc[0] += q0.x*xv0 + q1.x*xv1 + q2.x*xv2 + q3.x*xv3;
                acc[1] += q0.y*xv0 + q1.y*xv1 + q2.y*xv2 + q3.y*xv3;
                acc[2] += q0.z*xv0 + q1.z*xv1 + q2.z*xv2 + q3.z*xv3;
                acc[3] += q0.w*xv0 + q1.w*xv1 + q2.w*xv2 + q3.w*xv3;
            } else {
                float4 q0a = *(const float4*)&qsh[w][o0][0];
                float4 q0b = *(const float4*)&qsh[w][o0][4];
                float4 q1a = *(const float4*)&qsh[w][o0+1][0];
                float4 q1b = *(const float4*)&qsh[w][o0+1][4];
                float4 q2a = *(const float4*)&qsh[w][o0+2][0];
                float4 q2b = *(const float4*)&qsh[w][o0+2][4];
                float4 q3a = *(const float4*)&qsh[w][o0+3][0];
                float4 q3b = *(const float4*)&qsh[w][o0+3][4];
                acc[0] += q0a.x*xv0 + q1a.x*xv1 + q2a.x*xv2 + q3a.x*xv3;
                acc[1] += q0a.y*xv0 + q1a.y*xv1 + q2a.y*xv2 + q3a.y*xv3;
                acc[2] += q0a.z*xv0 + q1a.z*xv1 + q2a.z*xv2 + q3a.z*xv3;
                acc[3] += q0a.w*xv0 + q1a.w*xv1 + q2a.w*xv2 + q3a.w*xv3;
                acc[4] += q0b.x*xv0 + q1b.x*xv1 + q2b.x*xv2 + q3b.x*xv3;
                acc[5] += q0b.y*xv0 + q1b.y*xv1 + q2b.y*xv2 + q3b.y*xv3;
                acc[6] += q0b.z*xv0 + q1b.z*xv1 + q2b.z*xv2 + q3b.z*xv3;
                acc[7] += q0b.w*xv0 + q1b.w*xv1 + q2b.w*xv2 + q3b.w*xv3;
            }
        }
        if (j + 2 <= je) {
            int o0 = j - jb;
            int s0 = ssh[w][o0], s1 = ssh[w][o0+1];
            float xv0 = bf2f(hk[(size_t)s0*CIN]);
            float xv1 = bf2f(hk[(size_t)s1*CIN]);
            if constexpr (HPER == 2) {
                float2 q0 = *(const float2*)&qsh[w][o0][hg*2];
                float2 q1 = *(const float2*)&qsh[w][o0+1][hg*2];
                acc[0] += q0.x*xv0 + q1.x*xv1;
                acc[1] += q0.y*xv0 + q1.y*xv1;
            } else if constexpr (HPER == 4) {
                float4 q0 = *(const float4*)&qsh[w][o0][hg*4];
                float4 q1 = *(const float4*)&qsh[w][o0+1][hg*4];
                acc[0] += q0.x*xv0 + q1.x*xv1;
                acc[1] += q0.y*xv0 + q1.y*xv1;
                acc[2] += q0.z*xv0 + q1.z*xv1;
                acc[3] += q0.w*xv0 + q1.w*xv1;
            } else {
                float4 q0a = *(const float4*)&qsh[w][o0][0];
                float4 q0b = *(const float4*)&qsh[w][o0][4];
                float4 q1a = *(const float4*)&qsh[w][o0+1][0];
                float4 q1b = *(const float4*)&qsh[w][o0+1][4];
                acc[0] += q0a.x*xv0 + q1a.x*xv1;
                acc[1] += q0a.y*xv0 + q1a.y*xv1;
                acc[2] += q0a.z*xv0 + q1a.z*xv1;
                acc[3] += q0a.w*xv0 + q1a.w*xv1;
                acc[4] += q0b.x*xv0 + q1b.x*xv1;
                acc[5] += q0b.y*xv0 + q1b.y*xv1;
                acc[6] += q0b.z*xv0 + q1b.z*xv1;
                acc[7] += q0b.w*xv0 + q1b.w*xv1;
            }
            j += 2;
        }
        if (j < je) {
            int o0 = j - jb;
            int s0 = ssh[w][o0];
            float xv0 = bf2f(hk[(size_t)s0*CIN]);
            #pragma unroll
            for (int i = 0; i < HPER; ++i)
                acc[i] += qsh[w][o0][hg*HPER + i] * xv0;
        }
    }
    #pragma unroll
    for (int i = 0; i < HPER; ++i)
        g[(size_t)d*(8*CIN) + (hg*HPER + i)*CIN + k] = f2bf(acc[i]);
}

// ---------------- feast GEMM (bf16 out, optional a-epilogue) ---------------
template<int K, int O, int CH, bool AEPI>
__global__ __launch_bounds__(256) void gemm_feast(
        const unsigned short* __restrict__ g, const unsigned short* __restrict__ wp,
        const int* __restrict__ rowptr, const float* __restrict__ b,
        unsigned short* __restrict__ hout,
        const float* __restrict__ unext, float* __restrict__ aout) {
    constexpr int NS = K / 32;
    constexpr int NCT = O / 16;
    __shared__ unsigned short bsh[CH*NS*64*8];
    const int l = threadIdx.x & 63;
    const int w = threadIdx.x >> 6;
    const int base = blockIdx.x * 64 + w * 16;
    int arow = base + (l & 15); if (arow >= NN) arow = NN - 1;
    const int koff = (l >> 4) * 8;
    s8v af[NS];
    #pragma unroll
    for (int s = 0; s < NS; ++s)
        af[s] = *(const s8v*)(g + (size_t)arow*K + s*32 + koff);
    float invc[4];
    #pragma unroll
    for (int r = 0; r < 4; ++r) {
        int n = base + (l >> 4)*4 + r; if (n >= NN) n = NN - 1;
        invc[r] = 1.f / (float)(rowptr[n+1] - rowptr[n] + 1);
    }
    float apart[4][8];
    if constexpr (AEPI) {
        #pragma unroll
        for (int r = 0; r < 4; ++r)
            #pragma unroll
            for (int h = 0; h < 8; ++h) apart[r][h] = 0.f;
    }
    #pragma unroll 1
    for (int ct0 = 0; ct0 < NCT; ct0 += CH) {
        __syncthreads();
        const int4* sp = (const int4*)(wp + (size_t)ct0*NS*512);
        int4* dp = (int4*)bsh;
        #pragma unroll 1
        for (int i = threadIdx.x; i < CH*NS*64; i += 256) dp[i] = sp[i];
        __syncthreads();
        #pragma unroll 1
        for (int cc = 0; cc < CH; ++cc) {
            f4v accA = {0.f,0.f,0.f,0.f}, accB = {0.f,0.f,0.f,0.f};
            #pragma unroll
            for (int s = 0; s < NS/2; ++s) {
                s8v bf = *(const s8v*)(bsh + ((size_t)(cc*NS + s)*64 + l)*8);
                accA = __builtin_amdgcn_mfma_f32_16x16x32_bf16(af[s], bf, accA, 0, 0, 0);
            }
            #pragma unroll
            for (int s = NS/2; s < NS; ++s) {
                s8v bf = *(const s8v*)(bsh + ((size_t)(cc*NS + s)*64 + l)*8);
                accB = __builtin_amdgcn_mfma_f32_16x16x32_bf16(af[s], bf, accB, 0, 0, 0);
            }
            int col = (ct0 + cc)*16 + (l & 15);
            float bb = b[col];
            float uv[8];
            if constexpr (AEPI) {
                #pragma unroll
                for (int h = 0; h < 8; ++h) uv[h] = unext[col*8 + h];
            }
            #pragma unroll
            for (int r = 0; r < 4; ++r) {
                int n = base + (l >> 4)*4 + r;
                float v = fmaxf((accA[r]+accB[r])*invc[r] + bb, 0.f);
                if constexpr (AEPI) {
                    #pragma unroll
                    for (int h = 0; h < 8; ++h) apart[r][h] += v * uv[h];
                }
                if (n < NN) hout[(size_t)n*O + col] = f2bf(v);
            }
        }
    }
    if constexpr (AEPI) {
        #pragma unroll
        for (int r = 0; r < 4; ++r)
            #pragma unroll
            for (int h = 0; h < 8; ++h) {
                float v = apart[r][h];
                v += __shfl_xor(v, 1, 64);
                v += __shfl_xor(v, 2, 64);
                v += __shfl_xor(v, 4, 64);
                v += __shfl_xor(v, 8, 64);
                if ((l & 15) == 0) {
                    int n = base + (l >> 4)*4 + r;
                    if (n < NN) aout[(size_t)n*8 + h] = v;
                }
            }
    }
}

// ---------------- lin23 split-ct z reduction (512 rows/block) --------------
// grid (16 ctg, 98 row-groups): x-fastest dispatch puts all 16 ctg blocks of
// one row-group back-to-back -> h4 rows stay hot in L2/L3 across the 16 reads.
__global__ __launch_bounds__(256) void lin23z_kernel(
        const unsigned short* __restrict__ h4b, const unsigned short* __restrict__ w2p,
        const float* __restrict__ b2, const float* __restrict__ w3,
        float* __restrict__ z) {
    const int l = threadIdx.x & 63;
    const int w = threadIdx.x >> 6;
    const int ctg = blockIdx.x;                       // 16
    const int rowbase = blockIdx.y * 512 + w * 128;
    const int koff = (l >> 4) * 8;
    s8v bf0[4], bf1[4], bf2[4], bf3[4];
    #pragma unroll
    for (int s = 0; s < 4; ++s) {
        bf0[s] = *(const s8v*)(w2p + ((size_t)((ctg*4+0)*4 + s)*64 + l)*8);
        bf1[s] = *(const s8v*)(w2p + ((size_t)((ctg*4+1)*4 + s)*64 + l)*8);
        bf2[s] = *(const s8v*)(w2p + ((size_t)((ctg*4+2)*4 + s)*64 + l)*8);
        bf3[s] = *(const s8v*)(w2p + ((size_t)((ctg*4+3)*4 + s)*64 + l)*8);
    }
    float w3c[4], b2c[4];
    #pragma unroll
    for (int c = 0; c < 4; ++c) {
        int col = (ctg*4 + c)*16 + (l & 15);
        w3c[c] = w3[col]; b2c[c] = b2[col];
    }
    #pragma unroll 1
    for (int t = 0; t < 8; ++t) {
        int base = rowbase + t*16;
        if (base >= NN) break;
        int arow = base + (l & 15); if (arow >= NN) arow = NN - 1;
        s8v af[4];
        #pragma unroll
        for (int s = 0; s < 4; ++s)
            af[s] = *(const s8v*)(h4b + (size_t)arow*128 + s*32 + koff);
        float zp0 = 0.f, zp1 = 0.f, zp2 = 0.f, zp3 = 0.f;
        #pragma unroll
        for (int c = 0; c < 4; ++c) {
            const s8v* bf = (c == 0) ? bf0 : (c == 1) ? bf1 : (c == 2) ? bf2 : bf3;
            f4v accA = {0.f,0.f,0.f,0.f}, accB = {0.f,0.f,0.f,0.f};
            accA = __builtin_amdgcn_mfma_f32_16x16x32_bf16(af[0], bf[0], accA, 0, 0, 0);
            accA = __builtin_amdgcn_mfma_f32_16x16x32_bf16(af[1], bf[1], accA, 0, 0, 0);
            accB = __builtin_amdgcn_mfma_f32_16x16x32_bf16(af[2], bf[2], accB, 0, 0, 0);
            accB = __builtin_amdgcn_mfma_f32_16x16x32_bf16(af[3], bf[3], accB, 0, 0, 0);
            zp0 += fmaxf(accA[0]+accB[0] + b2c[c], 0.f) * w3c[c];
            zp1 += fmaxf(accA[1]+accB[1] + b2c[c], 0.f) * w3c[c];
            zp2 += fmaxf(accA[2]+accB[2] + b2c[c], 0.f) * w3c[c];
            zp3 += fmaxf(accA[3]+accB[3] + b2c[c], 0.f) * w3c[c];
        }
        #pragma unroll
        for (int m = 1; m < 16; m <<= 1) {
            zp0 += __shfl_xor(zp0, m, 64);
            zp1 += __shfl_xor(zp1, m, 64);
            zp2 += __shfl_xor(zp2, m, 64);
            zp3 += __shfl_xor(zp3, m, 64);
        }
        if ((l & 15) == 0) {
            int r0 = base + (l >> 4) * 4;
            if (r0+0 < NN) atomicAdd(&z[r0+0], zp0);
            if (r0+1 < NN) atomicAdd(&z[r0+1], zp1);
            if (r0+2 < NN) atomicAdd(&z[r0+2], zp2);
            if (r0+3 < NN) atomicAdd(&z[r0+3], zp3);
        }
    }
}

// ---------------- finish: sigmoid + balanced-BCE loss ----------------
__global__ void finish_kernel(const float* __restrict__ labels,
                              const float* __restrict__ z,
                              const float* __restrict__ b3,
                              float* __restrict__ p,
                              float* __restrict__ scal,
                              float* __restrict__ out, int nblk) {
    __shared__ float sh0[256], sh1[256], sh2[256];
    int tid = threadIdx.x;
    int n = blockIdx.x * 256 + tid;
    float pos = 0.f, sp = 0.f, sn = 0.f;
    if (n < NN) {
        float pv = 1.f / (1.f + expf(-(z[n] + b3[0])));
        p[n] = pv;
        float yv = labels[n];
        if (yv == 1.0f) { pos = 1.f; sp = -fmaxf(logf(pv), -100.f); }
        else            { sn = -fmaxf(logf(1.f - pv), -100.f); }
    }
    sh0[tid] = pos; sh1[tid] = sp; sh2[tid] = sn;
    __syncthreads();
    for (int off = 128; off; off >>= 1) {
        if (tid < off) {
            sh0[tid] += sh0[tid+off];
            sh1[tid] += sh1[tid+off];
            sh2[tid] += sh2[tid+off];
        }
        __syncthreads();
    }
    if (tid == 0) {
        atomicAdd(&scal[0], sh0[0]);
        atomicAdd(&scal[1], sh1[0]);
        atomicAdd(&scal[2], sh2[0]);
        __threadfence();
        int t = atomicAdd((int*)&scal[4], 1);
        if (t == nblk - 1) {
            float posT = atomicAdd(&scal[0], 0.f);
            float spT  = atomicAdd(&scal[1], 0.f);
            float snT  = atomicAdd(&scal[2], 0.f);
            out[0] = spT / (2.f*posT) + snT / (2.f*((float)NN - posT));
        }
    }
}

// ---------------- launch ----------------
extern "C" void kernel_launch(void* const* d_in, const int* in_sizes, int n_in,
                              void* d_out, int out_size, void* d_ws, size_t ws_size,
                              hipStream_t stream) {
    (void)in_sizes; (void)n_in; (void)out_size; (void)ws_size;
    const float* x   = (const float*)d_in[0];
    const int*   ei  = (const int*)d_in[1];
    const float* labels = (const float*)d_in[2];
    const float* l1w = (const float*)d_in[3];
    const float* l1b = (const float*)d_in[4];
    const float* cw[3] = {(const float*)d_in[5], (const float*)d_in[9],  (const float*)d_in[13]};
    const float* cu[3] = {(const float*)d_in[6], (const float*)d_in[10], (const float*)d_in[14]};
    const float* cc[3] = {(const float*)d_in[7], (const float*)d_in[11], (const float*)d_in[15]};
    const float* cb[3] = {(const float*)d_in[8], (const float*)d_in[12], (const float*)d_in[16]};
    const float* l2w = (const float*)d_in[17];
    const float* l2b = (const float*)d_in[18];
    const float* l3w = (const float*)d_in[19];
    const float* l3b = (const float*)d_in[20];
    const int* srcp = ei;
    const int* dstp = ei + NE;
    float* out = (float*)d_out;

    // ---- workspace (float units, 64B aligned) ----
    float* ws = (float*)d_ws;
    size_t off = 0;
    auto alloc = [&](size_t n) { float* p = ws + off; off += (n + 15) & ~(size_t)15; return p; };
    unsigned short* hA = (unsigned short*)alloc((size_t)NN*32);   // bf16: h1(N,16) / h3(N,64)
    unsigned short* hB = (unsigned short*)alloc((size_t)NN*64);   // bf16: h2(N,32) / h4(N,128)
    float* a  = alloc((size_t)NN*8);
    unsigned short* g   = (unsigned short*)alloc((size_t)NN*256);
    unsigned short* w2p = (unsigned short*)alloc(65536);
    unsigned short* wf1 = (unsigned short*)alloc(2048);
    unsigned short* wf2 = (unsigned short*)alloc(8192);
    unsigned short* wf3 = (unsigned short*)alloc(32768);
    float* z    = alloc(NN);
    float* scal = alloc(16);
    int* rowptr = (int*)alloc(50016);
    int* fill   = (int*)alloc(NN);
    int* fill2  = (int*)alloc(NN);
    int* ssrc   = (int*)alloc(NE);
    int* bpart  = (int*)alloc(256);

    const int SCAN_BLKS = (NN + 255) / 256;           // 196
    const int GB = (NN + 63) / 64;                    // 782
    const int PREP_BLKS = 106 + 587 + (NN + 63)/64;   // 1475

    // ---- prep + CSR build ----
    prep_kernel<<<PREP_BLKS, 256, 0, stream>>>(l2w, w2p, cw[0], wf1, cw[1], wf2,
                                               cw[2], wf3, fill, fill2, z, scal,
                                               x, l1w, l1b, cu[0], hA, a);
    hist_kernel<<<(NE+255)/256, 256, 0, stream>>>(dstp, fill);
    scan1_kernel<<<SCAN_BLKS, 256, 0, stream>>>(fill, rowptr, bpart);
    scanfix_kernel<<<SCAN_BLKS, 256, 0, stream>>>(rowptr, bpart, SCAN_BLKS);
    scatter_kernel<<<(NE+255)/256, 256, 0, stream>>>(srcp, dstp, rowptr, fill2, ssrc);

    // ---- conv1: cin=16 -> O=32 (hA -> hB); epilogue a2 ----
    agg_kernel<16><<<NN/4, 256, 0, stream>>>(hA, a, cc[0], rowptr, ssrc, g);
    gemm_feast<128,32,2,true><<<GB, 256, 0, stream>>>(g, wf1, rowptr, cb[0], hB, cu[1], a);

    // ---- conv2: cin=32 -> O=64 (hB -> hA); epilogue a3 ----
    agg_kernel<32><<<NN/4, 256, 0, stream>>>(hB, a, cc[1], rowptr, ssrc, g);
    gemm_feast<256,64,4,true><<<GB, 256, 0, stream>>>(g, wf2, rowptr, cb[1], hA, cu[2], a);

    // ---- conv3: cin=64 -> O=128 (hA -> hB) ----
    agg_kernel<64><<<NN/4, 256, 0, stream>>>(hA, a, cc[2], rowptr, ssrc, g);
    gemm_feast<512,128,2,false><<<GB, 256, 0, stream>>>(g, wf3, rowptr, cb[2], hB, nullptr, nullptr);

    // ---- lin2+lin3 z reduction (ctg-major grid for h4 L2 reuse) ----
    lin23z_kernel<<<dim3(16, (NN+511)/512), 256, 0, stream>>>(hB, w2p, l2b, l3w, z);
    finish_kernel<<<SCAN_BLKS, 256, 0, stream>>>(labels, z, l3b, out + 1, scal, out, SCAN_BLKS);
}